// Round 4
// baseline (490.472 us; speedup 1.0000x reference)
//
#include <hip/hip_runtime.h>
#include <stdint.h>

#define BATCH 4
#define NPTS 8192
#define KNN_K 16
#define GRID 24
#define NCELL (GRID * GRID * GRID)  // 13824
#define NCELLP (NCELL + 8)          // offs stride (sentinel slot)

typedef unsigned long long u64;
typedef unsigned short u16;

// ws layout (bytes)
#define WS_IDX 0u          // u16[4*8192*16]            = 1,048,576
#define WS_LT 1048576u     // float[4*8192*192]         = 25,165,824
#define WS_CNT 26214400u   // int[4*13824]              = 221,184
#define WS_OFF 26435584u   // int[4*13832]              = 221,312
#define WS_CUR 26656896u   // int[4*13824]              = 221,184
#define WS_SP 26878080u    // float4[4*8192]            = 524,288
#define WS_GP 27402368u    // float[4*8]                = 128
#define WS_SIDX 27402496u  // u16[4*8192]               = 65,536

__device__ __forceinline__ int cellof(float v, float o, float invs) {
  int c = (int)((v - o) * invs);
  return c < GRID - 1 ? c : GRID - 1;
}

// ---------------------------------------------------------------- K0: bbox + zero counters
__global__ __launch_bounds__(256) void k_minmax(const float4* __restrict__ xytp,
                                                float* __restrict__ gp,
                                                int* __restrict__ cnt) {
  const int b = blockIdx.x, t = threadIdx.x;
  for (int c = t; c < NCELL; c += 256) cnt[b * NCELL + c] = 0;
  const float4* pb = xytp + (b << 13);
  float mnx = INFINITY, mny = INFINITY, mnz = INFINITY;
  float mxx = -INFINITY, mxy = -INFINITY, mxz = -INFINITY;
  for (int i = t; i < NPTS; i += 256) {
    float4 p = pb[i];
    mnx = fminf(mnx, p.x); mny = fminf(mny, p.y); mnz = fminf(mnz, p.z);
    mxx = fmaxf(mxx, p.x); mxy = fmaxf(mxy, p.y); mxz = fmaxf(mxz, p.z);
  }
#pragma unroll
  for (int d = 1; d < 64; d <<= 1) {
    mnx = fminf(mnx, __shfl_xor(mnx, d)); mny = fminf(mny, __shfl_xor(mny, d));
    mnz = fminf(mnz, __shfl_xor(mnz, d)); mxx = fmaxf(mxx, __shfl_xor(mxx, d));
    mxy = fmaxf(mxy, __shfl_xor(mxy, d)); mxz = fmaxf(mxz, __shfl_xor(mxz, d));
  }
  __shared__ float red[4][6];
  const int lane = t & 63, wv = t >> 6;
  if (lane == 0) {
    red[wv][0] = mnx; red[wv][1] = mny; red[wv][2] = mnz;
    red[wv][3] = mxx; red[wv][4] = mxy; red[wv][5] = mxz;
  }
  __syncthreads();
  if (t == 0) {
    for (int w = 1; w < 4; ++w) {
      red[0][0] = fminf(red[0][0], red[w][0]);
      red[0][1] = fminf(red[0][1], red[w][1]);
      red[0][2] = fminf(red[0][2], red[w][2]);
      red[0][3] = fmaxf(red[0][3], red[w][3]);
      red[0][4] = fmaxf(red[0][4], red[w][4]);
      red[0][5] = fmaxf(red[0][5], red[w][5]);
    }
    float rmax = fmaxf(red[0][3] - red[0][0],
                       fmaxf(red[0][4] - red[0][1], red[0][5] - red[0][2]));
    float s = rmax / (float)GRID;
    float* g = gp + b * 8;
    g[0] = red[0][0]; g[1] = red[0][1]; g[2] = red[0][2];
    g[3] = s; g[4] = 1.0f / s;
  }
}

// ---------------------------------------------------------------- K2: count
__global__ __launch_bounds__(256) void k_count(const float4* __restrict__ xytp,
                                               const float* __restrict__ gp,
                                               int* __restrict__ cnt) {
  int i = blockIdx.x * 256 + threadIdx.x;
  int b = i >> 13;
  const float* g = gp + b * 8;
  float4 p = xytp[i];
  int cx = cellof(p.x, g[0], g[4]);
  int cy = cellof(p.y, g[1], g[4]);
  int cz = cellof(p.z, g[2], g[4]);
  atomicAdd(&cnt[b * NCELL + (cz * GRID + cy) * GRID + cx], 1);
}

// ---------------------------------------------------------------- K3: exclusive scan
// offs has stride NCELLP with offs[b*NCELLP + NCELL] = NPTS sentinel, so
// end(cell c) == offs[c+1] works for every cell including the last.
__global__ __launch_bounds__(1024) void k_scan(const int* __restrict__ cnt,
                                               int* __restrict__ offs,
                                               int* __restrict__ curs) {
  __shared__ int wsum[16];
  const int b = blockIdx.x, t = threadIdx.x;
  const int base = b * NCELL;
  const int base2 = b * NCELLP;
  const int lo = t * 14;
  const int hi = lo + 14 < NCELL ? lo + 14 : NCELL;
  int s = 0;
  for (int c = lo; c < hi; ++c) s += cnt[base + c];
  const int lane = t & 63, wv = t >> 6;
  int v = s;
#pragma unroll
  for (int d = 1; d < 64; d <<= 1) {
    int u = __shfl_up(v, d);
    if (lane >= d) v += u;
  }
  if (lane == 63) wsum[wv] = v;
  __syncthreads();
  if (wv == 0 && lane < 16) {
    int x = wsum[lane];
#pragma unroll
    for (int d = 1; d < 16; d <<= 1) {
      int u = __shfl_up(x, d, 16);
      if (lane >= d) x += u;
    }
    wsum[lane] = x;
  }
  __syncthreads();
  int excl = (wv > 0 ? wsum[wv - 1] : 0) + v - s;
  for (int c = lo; c < hi; ++c) {
    offs[base2 + c] = excl;
    curs[base + c] = excl;
    excl += cnt[base + c];
  }
  if (hi == NCELL) offs[base2 + NCELL] = excl;  // == NPTS
}

// ---------------------------------------------------------------- K4: scatter (cell-sorted points, sq in .w, idx in sidx)
__global__ __launch_bounds__(256) void k_scatter(const float4* __restrict__ xytp,
                                                 const float* __restrict__ gp,
                                                 int* __restrict__ curs,
                                                 float4* __restrict__ spts,
                                                 u16* __restrict__ sidx) {
  int i = blockIdx.x * 256 + threadIdx.x;
  int b = i >> 13, n = i & 8191;
  const float* g = gp + b * 8;
  float4 p = xytp[i];
  int cx = cellof(p.x, g[0], g[4]);
  int cy = cellof(p.y, g[1], g[4]);
  int cz = cellof(p.z, g[2], g[4]);
  int pos = atomicAdd(&curs[b * NCELL + (cz * GRID + cy) * GRID + cx], 1);
  float sq = fmaf(p.z, p.z, fmaf(p.y, p.y, p.x * p.x));
  spts[(b << 13) + pos] = make_float4(p.x, p.y, p.z, sq);
  sidx[(b << 13) + pos] = (u16)n;
}

// ---------------------------------------------------------------- K5: grid KNN query
// R13: team-wide pruning threshold tau = max over lanes of lane-best
// (lst[0]).  The 16 lane-bests are 16 distinct real candidates, so any
// candidate with key > tau is beaten by >=16 existing candidates ->
// provably outside the team top-16 -> skip the (expensive, wave-
// divergent) 16-deep insert chain.  tau is refreshed per segment via a
// 4-step shfl_xor u64 max-reduce (~20 ops).  The count-based stop is
// unaffected: the 16 smallest keys are each <= tau and retained in
// their lane's top-16.  Structure otherwise identical to R11/R10.
#define INSERTC(Af, OI)                                                      \
  {                                                                          \
    float dot = q.x * (Af).x;                                                \
    dot = fmaf(q.y, (Af).y, dot);                                            \
    dot = fmaf(q.z, (Af).z, dot);                                            \
    float d2 = (qsq + (Af).w) - 2.0f * dot;                                  \
    unsigned u = __float_as_uint(d2);                                        \
    u ^= (0x80000000u | (unsigned)((int)u >> 31));                           \
    u64 key = ((u64)u << 32) | (OI);                                         \
    if (key < lst[15] && key < tau) {                                        \
      u64 x = key;                                                           \
      _Pragma("unroll") for (int p = 0; p < 16; ++p) {                       \
        bool sw = x < lst[p];                                                \
        u64 a = lst[p];                                                      \
        lst[p] = sw ? x : a;                                                 \
        x = sw ? a : x;                                                      \
      }                                                                      \
    }                                                                        \
  }

#define SCANSEG(S0, S1)                                                      \
  {                                                                          \
    int j = (S0) + l;                                                        \
    for (; j + 16 < (S1); j += 32) {                                         \
      float4 A0 = sp[j];                                                     \
      unsigned o0 = sx[j];                                                   \
      float4 A1 = sp[j + 16];                                                \
      unsigned o1 = sx[j + 16];                                              \
      INSERTC(A0, o0)                                                        \
      INSERTC(A1, o1)                                                        \
    }                                                                        \
    if (j < (S1)) {                                                          \
      float4 A0 = sp[j];                                                     \
      unsigned o0 = sx[j];                                                   \
      INSERTC(A0, o0)                                                        \
    }                                                                        \
  }

__global__ __launch_bounds__(64) void k_query(const float4* __restrict__ spts,
                                              const u16* __restrict__ sidx,
                                              const int* __restrict__ offs,
                                              const float* __restrict__ gp,
                                              u16* __restrict__ oidx) {
  __shared__ u64 kb[16 * 64];  // 8 KB merge keys: kb[(slot<<6) + tid]
  const int tid = threadIdx.x;
  const int l = tid & 15;       // team lane
  const int team = tid >> 4;    // 0..3 (query within block)
  const int lane = tid & 63;    // wave lane (== tid)
  const int qid = blockIdx.x * 4 + team;
  const int b = qid >> 13, i = qid & 8191;
  const float4* __restrict__ sp = spts + (b << 13);
  const u16* __restrict__ sx = sidx + (b << 13);
  const int* __restrict__ ob = offs + b * NCELLP;
  const float* g = gp + b * 8;
  float4 q = sp[i];
  const float qsq = q.w;  // sq precomputed
  const unsigned orig = sx[i];
  const int cx = cellof(q.x, g[0], g[4]);
  const int cy = cellof(q.y, g[1], g[4]);
  const int cz = cellof(q.z, g[2], g[4]);
  const float s = g[3];

  u64 lst[16];
#pragma unroll
  for (int p = 0; p < 16; ++p) lst[p] = ~0ULL;
  u64 tau = ~0ULL;  // team-wide prune bound (max of lane bests)

  const int tb = lane & 48;  // team base within wave

  for (int r = 0; r <= GRID; ++r) {
    const int W = 2 * r + 1;
    const int nent = 2 * W * W;
    for (int base = 0; base < nent; base += 16) {
      // phase A: each lane loads bounds of its own entry (parallel chains)
      int ms0 = 0, ms1 = 0;
      const int eid = base + l;
      if (eid < nent) {
        const int rid = eid >> 1, side = eid & 1;
        const int dz = rid / W - r;
        const int dy = rid % W - r;
        const int z2 = cz + dz, y2 = cy + dy;
        if ((unsigned)z2 < GRID && (unsigned)y2 < GRID) {
          const int rowb = (z2 * GRID + y2) * GRID;
          const bool bdry = (dz == -r) || (dz == r) || (dy == -r) || (dy == r);
          if (bdry) {
            if (side == 0) {
              const int xl = cx - r < 0 ? 0 : cx - r;
              const int xh = cx + r > GRID - 1 ? GRID - 1 : cx + r;
              ms0 = ob[rowb + xl];
              ms1 = ob[rowb + xh + 1];
            }
          } else {
            const int x2 = side ? cx + r : cx - r;
            if ((unsigned)x2 < GRID) {
              ms0 = ob[rowb + x2];
              ms1 = ob[rowb + x2 + 1];
            }
          }
        }
      }
      // phase B: ballot-compact non-empty segments, broadcast, scan
      unsigned m = (unsigned)((__ballot(ms1 > ms0) >> tb) & 0xFFFFull);
      while (m) {
        const int e = __ffs(m) - 1;
        m &= m - 1;
        const int s0 = __shfl(ms0, tb + e);
        const int s1 = __shfl(ms1, tb + e);
        SCANSEG(s0, s1)
        // refresh tau: max over team lanes of lane-best (lst[0]).
        u64 t0 = lst[0];
        u64 t1 = __shfl_xor(t0, 1);  t0 = t0 > t1 ? t0 : t1;
        t1 = __shfl_xor(t0, 2);      t0 = t0 > t1 ? t0 : t1;
        t1 = __shfl_xor(t0, 4);      t0 = t0 > t1 ? t0 : t1;
        t1 = __shfl_xor(t0, 8);      t0 = t0 > t1 ? t0 : t1;
        tau = t0;
      }
    }
    // team stop check (R10): count team candidates with d2 <= (r*s)^2 - eps.
    const float rs = (float)r * s;
    const float T = fmaf(rs, rs, -1e-4f);
    unsigned tu = __float_as_uint(T);
    tu ^= (0x80000000u | (unsigned)((int)tu >> 31));
    int c = 0;
#pragma unroll
    for (int p = 0; p < 16; ++p) c += ((unsigned)(lst[p] >> 32) <= tu) ? 1 : 0;
    c += __shfl_xor(c, 1);
    c += __shfl_xor(c, 2);
    c += __shfl_xor(c, 4);
    c += __shfl_xor(c, 8);
    if (c >= 16) break;
  }

  // ---- merge 16 sorted lists per query (4 stages) ----
#pragma unroll
  for (int p = 0; p < 16; ++p) kb[(p << 6) + tid] = lst[p];
  __syncthreads();

  const int cbase = team << 4;
  u64 rb[16];
#pragma unroll
  for (int st = 0; st < 3; ++st) {
    const int stride = 1 << st;        // 1, 2, 4
    const int nm = 8 >> st;            // 8, 4, 2 merges
    const bool act = (l < nm);
    if (act) {
      const int la = cbase + (2 * l) * stride;
      const int lb = la + stride;
      int pa = 0, pb = 0;
      u64 ka = kb[la], kv = kb[lb];
#pragma unroll
      for (int k = 0; k < 16; ++k) {
        bool ta = ka < kv;
        rb[k] = ta ? ka : kv;
        if (ta) {
          ++pa;
          ka = (pa < 16) ? kb[(pa << 6) + la] : ~0ULL;
        } else {
          ++pb;
          kv = (pb < 16) ? kb[(pb << 6) + lb] : ~0ULL;
        }
      }
    }
    __syncthreads();
    if (act) {
      const int la = cbase + (2 * l) * (1 << st);
#pragma unroll
      for (int p = 0; p < 16; ++p) kb[(p << 6) + la] = rb[p];
    }
    __syncthreads();
  }
  if (l == 0) {  // final: merge (cbase, cbase+8) -> output
    const int la = cbase, lb = cbase + 8;
    int pa = 0, pb = 0;
    u64 ka = kb[la], kv = kb[lb];
    unsigned pk[8];
#pragma unroll
    for (int k = 0; k < 16; ++k) {
      bool ta = ka < kv;
      u64 sel = ta ? ka : kv;
      unsigned id16 = (unsigned)(sel & 0xFFFFull);
      if (k & 1)
        pk[k >> 1] |= id16 << 16;
      else
        pk[k >> 1] = id16;
      if (ta) {
        ++pa;
        ka = (pa < 16) ? kb[(pa << 6) + la] : ~0ULL;
      } else {
        ++pb;
        kv = (pb < 16) ? kb[(pb << 6) + lb] : ~0ULL;
      }
    }
    unsigned* od = (unsigned*)(oidx + (((size_t)(b << 13) + orig) << 4));
#pragma unroll
    for (int k = 0; k < 8; ++k) od[k] = pk[k];
  }
}

// ---------------------------------------------------------------- K6: lt = feat @ lt_w + lt_b
__global__ __launch_bounds__(256) void k_lt(const float* __restrict__ feat,
                                            const float* __restrict__ ltw,
                                            const float* __restrict__ ltb,
                                            float* __restrict__ lt) {
  __shared__ float sw[64][196];
  __shared__ float sf[32][68];
  const int tid = threadIdx.x;
  const int r0 = blockIdx.x * 32;
#pragma unroll
  for (int i = 0; i < 12; ++i) {
    int v = tid + i * 256;
    float4 w4 = ((const float4*)ltw)[v];
    int row = (v * 4) / 192, col = (v * 4) % 192;
    *(float4*)&sw[row][col] = w4;
  }
#pragma unroll
  for (int i = 0; i < 2; ++i) {
    int v = tid + i * 256;
    int row = v >> 4, c4 = v & 15;
    float4 f4 = ((const float4*)(feat + (size_t)(r0 + row) * 64))[c4];
    *(float4*)&sf[row][c4 * 4] = f4;
  }
  __syncthreads();
  const int r = tid >> 3;
  const int c0 = (tid & 7) * 24;
  float acc[24];
#pragma unroll
  for (int ll = 0; ll < 24; ++ll) acc[ll] = ltb[c0 + ll];
#pragma unroll 4
  for (int j = 0; j < 64; ++j) {
    float f = sf[r][j];
#pragma unroll
    for (int l4 = 0; l4 < 6; ++l4) {
      float4 w4 = *(const float4*)&sw[j][c0 + l4 * 4];
      acc[l4 * 4 + 0] = fmaf(f, w4.x, acc[l4 * 4 + 0]);
      acc[l4 * 4 + 1] = fmaf(f, w4.y, acc[l4 * 4 + 1]);
      acc[l4 * 4 + 2] = fmaf(f, w4.z, acc[l4 * 4 + 2]);
      acc[l4 * 4 + 3] = fmaf(f, w4.w, acc[l4 * 4 + 3]);
    }
  }
  float* orow = lt + (size_t)(r0 + r) * 192 + c0;
#pragma unroll
  for (int l4 = 0; l4 < 6; ++l4)
    *(float4*)&orow[l4 * 4] = make_float4(acc[l4 * 4], acc[l4 * 4 + 1],
                                          acc[l4 * 4 + 2], acc[l4 * 4 + 3]);
}

// ---------------------------------------------------------------- K7: main
// R12: online softmax (no pre/apd/xk arrays), prefetch-1 psi/alp gathers,
// DPP+readlane LN reductions (VALU pipe) instead of __shfl_xor (DS pipe).
// DPP ctrl must be a compile-time constant -> template parameter.
template <int CTRL>
__device__ __forceinline__ float dpp_add_f(float x) {
  int y = __builtin_amdgcn_update_dpp(0, __float_as_int(x), CTRL, 0xf, 0xf,
                                      true);
  return x + __int_as_float(y);
}
// full-wave (64-lane) sum -> wave-uniform via readlane 63.
// row_shr 1/2/4/8: lane15 of each row16 = row sum; row_bcast:15 add:
// lane31 = rows0+1, lane63 = rows2+3; row_bcast:31 add: lane63 = total.
__device__ __forceinline__ float wave_sum64(float x) {
  x = dpp_add_f<0x111>(x);  // row_shr:1
  x = dpp_add_f<0x112>(x);  // row_shr:2
  x = dpp_add_f<0x114>(x);  // row_shr:4
  x = dpp_add_f<0x118>(x);  // row_shr:8
  x = dpp_add_f<0x142>(x);  // row_bcast:15
  x = dpp_add_f<0x143>(x);  // row_bcast:31
  return __int_as_float(__builtin_amdgcn_readlane(__float_as_int(x), 63));
}

__global__ __launch_bounds__(256) void k_main(
    const float4* __restrict__ xytp, const float* __restrict__ lt,
    const u16* __restrict__ knn, const float* __restrict__ pe_w1,
    const float* __restrict__ pe_b1, const float* __restrict__ pe_w2,
    const float* __restrict__ pe_b2, const float* __restrict__ ln_g,
    const float* __restrict__ ln_b, float* __restrict__ out) {
  __shared__ float s_h[4][16][64];
  const int lane = threadIdx.x & 63;
  const int wave = threadIdx.x >> 6;
  const int pid = __builtin_amdgcn_readfirstlane(blockIdx.x * 4 + wave);
  const int b = pid >> 13;
  const int n = pid & 8191;

  float w1c[4];
#pragma unroll
  for (int d = 0; d < 4; ++d) w1c[d] = pe_w1[d * 64 + lane];
  const float b1c = pe_b1[lane];
  float w2c[64];
#pragma unroll
  for (int j = 0; j < 64; ++j) w2c[j] = pe_w2[j * 64 + lane];
  const float b2c = pe_b2[lane];
  const float gc = ln_g[lane], bc = ln_b[lane];

  int nb[16];
#pragma unroll
  for (int k = 0; k < 16; ++k) nb[k] = knn[pid * 16 + k];

  const float* __restrict__ ltb = lt + (size_t)(b << 13) * 192;
  const float vc = ltb[(size_t)n * 192 + lane];

  const float4 qv = xytp[(b << 13) + n];
#pragma unroll
  for (int k = 0; k < 16; ++k) {
    float4 g = xytp[(b << 13) + nb[k]];
    float r0 = qv.x - g.x, r1 = qv.y - g.y, r2 = qv.z - g.z, r3 = qv.w - g.w;
    float h = fmaf(r3, w1c[3],
                   fmaf(r2, w1c[2], fmaf(r1, w1c[1], fmaf(r0, w1c[0], b1c))));
    s_h[wave][k][lane] = fmaxf(h, 0.0f);
  }
  __syncthreads();

  float psi_c = ltb[(size_t)nb[0] * 192 + 64 + lane];
  float alp_c = ltb[(size_t)nb[0] * 192 + 128 + lane];
  float m = -INFINITY, se = 0.f, oacc = 0.f;
#pragma unroll
  for (int k = 0; k < 16; ++k) {
    float psi_n = 0.f, alp_n = 0.f;
    if (k < 15) {  // prefetch next neighbor's psi/alp (distance-1)
      const float* row = ltb + (size_t)nb[k + 1] * 192;
      psi_n = row[64 + lane];
      alp_n = row[128 + lane];
    }
    float acc = b2c;
#pragma unroll
    for (int j4 = 0; j4 < 16; ++j4) {
      float4 h4 = *(const float4*)&s_h[wave][k][j4 * 4];
      acc = fmaf(h4.x, w2c[j4 * 4 + 0], acc);
      acc = fmaf(h4.y, w2c[j4 * 4 + 1], acc);
      acc = fmaf(h4.z, w2c[j4 * 4 + 2], acc);
      acc = fmaf(h4.w, w2c[j4 * 4 + 3], acc);
    }
    const float pre = (vc - psi_c) + acc;
    const float apd = alp_c + acc;
    const float sm = wave_sum64(pre);
    const float ssm = wave_sum64(pre * pre);
    const float mu = sm * 0.015625f;
    const float var = fmaf(ssm, 0.015625f, -mu * mu);
    const float inv = rsqrtf(var + 1e-5f);
    const float x = fmaf((pre - mu) * inv, gc, bc) * 0.125f;
    // online softmax update (first iter: m=-inf -> corr = exp(-inf) = 0)
    const float mn = fmaxf(m, x);
    const float corr = __expf(m - mn);
    const float e = __expf(x - mn);
    se = fmaf(se, corr, e);
    oacc = fmaf(oacc, corr, e * apd);
    m = mn;
    psi_c = psi_n;
    alp_c = alp_n;
  }
  out[(size_t)pid * 64 + lane] = oacc / se;
}

// ---------------------------------------------------------------- launch
extern "C" void kernel_launch(void* const* d_in, const int* in_sizes, int n_in,
                              void* d_out, int out_size, void* d_ws,
                              size_t ws_size, hipStream_t stream) {
  const float4* xytp = (const float4*)d_in[0];
  const float* features = (const float*)d_in[1];
  const float* pe_w1 = (const float*)d_in[2];
  const float* pe_b1 = (const float*)d_in[3];
  const float* pe_w2 = (const float*)d_in[4];
  const float* pe_b2 = (const float*)d_in[5];
  const float* lt_w = (const float*)d_in[6];
  const float* lt_b = (const float*)d_in[7];
  const float* ln_g = (const float*)d_in[8];
  const float* ln_b = (const float*)d_in[9];
  float* out = (float*)d_out;

  char* ws = (char*)d_ws;
  u16* idxbuf = (u16*)(ws + WS_IDX);
  float* lt = (float*)(ws + WS_LT);
  int* cnt = (int*)(ws + WS_CNT);
  int* offs = (int*)(ws + WS_OFF);
  int* curs = (int*)(ws + WS_CUR);
  float4* spts = (float4*)(ws + WS_SP);
  float* gp = (float*)(ws + WS_GP);
  u16* sidx = (u16*)(ws + WS_SIDX);

  k_minmax<<<BATCH, 256, 0, stream>>>(xytp, gp, cnt);
  k_count<<<(BATCH * NPTS) / 256, 256, 0, stream>>>(xytp, gp, cnt);
  k_scan<<<BATCH, 1024, 0, stream>>>(cnt, offs, curs);
  k_scatter<<<(BATCH * NPTS) / 256, 256, 0, stream>>>(xytp, gp, curs, spts,
                                                      sidx);
  k_query<<<(BATCH * NPTS) / 4, 64, 0, stream>>>(spts, sidx, offs, gp,
                                                 idxbuf);
  k_lt<<<(BATCH * NPTS) / 32, 256, 0, stream>>>(features, lt_w, lt_b, lt);
  k_main<<<(BATCH * NPTS) / 4, 256, 0, stream>>>(xytp, lt, idxbuf, pe_w1,
                                                 pe_b1, pe_w2, pe_b2, ln_g,
                                                 ln_b, out);
}

// Round 5
// 468.991 us; speedup vs baseline: 1.0458x; 1.0458x over previous
//
#include <hip/hip_runtime.h>
#include <stdint.h>

#define BATCH 4
#define NPTS 8192
#define KNN_K 16
#define GRID 24
#define NCELL (GRID * GRID * GRID)  // 13824
#define NCELLP (NCELL + 8)          // offs stride (sentinel slot)

typedef unsigned long long u64;
typedef unsigned short u16;

// ws layout (bytes)
#define WS_IDX 0u          // u16[4*8192*16]            = 1,048,576
#define WS_LT 1048576u     // float[4*8192*192]         = 25,165,824
#define WS_CNT 26214400u   // int[4*13824]              = 221,184
#define WS_OFF 26435584u   // int[4*13832]              = 221,312
#define WS_CUR 26656896u   // int[4*13824]              = 221,184
#define WS_SP 26878080u    // float4[4*8192]            = 524,288
#define WS_GP 27402368u    // float[4*8]                = 128
#define WS_SIDX 27402496u  // u16[4*8192]               = 65,536

__device__ __forceinline__ int cellof(float v, float o, float invs) {
  int c = (int)((v - o) * invs);
  return c < GRID - 1 ? c : GRID - 1;
}

// ---------------------------------------------------------------- K0: bbox + zero counters
__global__ __launch_bounds__(256) void k_minmax(const float4* __restrict__ xytp,
                                                float* __restrict__ gp,
                                                int* __restrict__ cnt) {
  const int b = blockIdx.x, t = threadIdx.x;
  for (int c = t; c < NCELL; c += 256) cnt[b * NCELL + c] = 0;
  const float4* pb = xytp + (b << 13);
  float mnx = INFINITY, mny = INFINITY, mnz = INFINITY;
  float mxx = -INFINITY, mxy = -INFINITY, mxz = -INFINITY;
  for (int i = t; i < NPTS; i += 256) {
    float4 p = pb[i];
    mnx = fminf(mnx, p.x); mny = fminf(mny, p.y); mnz = fminf(mnz, p.z);
    mxx = fmaxf(mxx, p.x); mxy = fmaxf(mxy, p.y); mxz = fmaxf(mxz, p.z);
  }
#pragma unroll
  for (int d = 1; d < 64; d <<= 1) {
    mnx = fminf(mnx, __shfl_xor(mnx, d)); mny = fminf(mny, __shfl_xor(mny, d));
    mnz = fminf(mnz, __shfl_xor(mnz, d)); mxx = fmaxf(mxx, __shfl_xor(mxx, d));
    mxy = fmaxf(mxy, __shfl_xor(mxy, d)); mxz = fmaxf(mxz, __shfl_xor(mxz, d));
  }
  __shared__ float red[4][6];
  const int lane = t & 63, wv = t >> 6;
  if (lane == 0) {
    red[wv][0] = mnx; red[wv][1] = mny; red[wv][2] = mnz;
    red[wv][3] = mxx; red[wv][4] = mxy; red[wv][5] = mxz;
  }
  __syncthreads();
  if (t == 0) {
    for (int w = 1; w < 4; ++w) {
      red[0][0] = fminf(red[0][0], red[w][0]);
      red[0][1] = fminf(red[0][1], red[w][1]);
      red[0][2] = fminf(red[0][2], red[w][2]);
      red[0][3] = fmaxf(red[0][3], red[w][3]);
      red[0][4] = fmaxf(red[0][4], red[w][4]);
      red[0][5] = fmaxf(red[0][5], red[w][5]);
    }
    float rmax = fmaxf(red[0][3] - red[0][0],
                       fmaxf(red[0][4] - red[0][1], red[0][5] - red[0][2]));
    float s = rmax / (float)GRID;
    float* g = gp + b * 8;
    g[0] = red[0][0]; g[1] = red[0][1]; g[2] = red[0][2];
    g[3] = s; g[4] = 1.0f / s;
  }
}

// ---------------------------------------------------------------- K2: count
__global__ __launch_bounds__(256) void k_count(const float4* __restrict__ xytp,
                                               const float* __restrict__ gp,
                                               int* __restrict__ cnt) {
  int i = blockIdx.x * 256 + threadIdx.x;
  int b = i >> 13;
  const float* g = gp + b * 8;
  float4 p = xytp[i];
  int cx = cellof(p.x, g[0], g[4]);
  int cy = cellof(p.y, g[1], g[4]);
  int cz = cellof(p.z, g[2], g[4]);
  atomicAdd(&cnt[b * NCELL + (cz * GRID + cy) * GRID + cx], 1);
}

// ---------------------------------------------------------------- K3: exclusive scan
// offs has stride NCELLP with offs[b*NCELLP + NCELL] = NPTS sentinel, so
// end(cell c) == offs[c+1] works for every cell including the last.
__global__ __launch_bounds__(1024) void k_scan(const int* __restrict__ cnt,
                                               int* __restrict__ offs,
                                               int* __restrict__ curs) {
  __shared__ int wsum[16];
  const int b = blockIdx.x, t = threadIdx.x;
  const int base = b * NCELL;
  const int base2 = b * NCELLP;
  const int lo = t * 14;
  const int hi = lo + 14 < NCELL ? lo + 14 : NCELL;
  int s = 0;
  for (int c = lo; c < hi; ++c) s += cnt[base + c];
  const int lane = t & 63, wv = t >> 6;
  int v = s;
#pragma unroll
  for (int d = 1; d < 64; d <<= 1) {
    int u = __shfl_up(v, d);
    if (lane >= d) v += u;
  }
  if (lane == 63) wsum[wv] = v;
  __syncthreads();
  if (wv == 0 && lane < 16) {
    int x = wsum[lane];
#pragma unroll
    for (int d = 1; d < 16; d <<= 1) {
      int u = __shfl_up(x, d, 16);
      if (lane >= d) x += u;
    }
    wsum[lane] = x;
  }
  __syncthreads();
  int excl = (wv > 0 ? wsum[wv - 1] : 0) + v - s;
  for (int c = lo; c < hi; ++c) {
    offs[base2 + c] = excl;
    curs[base + c] = excl;
    excl += cnt[base + c];
  }
  if (hi == NCELL) offs[base2 + NCELL] = excl;  // == NPTS
}

// ---------------------------------------------------------------- K4: scatter (cell-sorted points, sq in .w, idx in sidx)
__global__ __launch_bounds__(256) void k_scatter(const float4* __restrict__ xytp,
                                                 const float* __restrict__ gp,
                                                 int* __restrict__ curs,
                                                 float4* __restrict__ spts,
                                                 u16* __restrict__ sidx) {
  int i = blockIdx.x * 256 + threadIdx.x;
  int b = i >> 13, n = i & 8191;
  const float* g = gp + b * 8;
  float4 p = xytp[i];
  int cx = cellof(p.x, g[0], g[4]);
  int cy = cellof(p.y, g[1], g[4]);
  int cz = cellof(p.z, g[2], g[4]);
  int pos = atomicAdd(&curs[b * NCELL + (cz * GRID + cy) * GRID + cx], 1);
  float sq = fmaf(p.z, p.z, fmaf(p.y, p.y, p.x * p.x));
  spts[(b << 13) + pos] = make_float4(p.x, p.y, p.z, sq);
  sidx[(b << 13) + pos] = (u16)n;
}

// ---------------------------------------------------------------- K5: grid KNN query
// R14: tau reverted (R4 post-mortem: lists never fill -> prune can't
// fire; per-segment u64 shfl reduce added latency).  LDS merge buffer
// (8KB -> occupancy capped at 5 waves/SIMD = the measured 17%) replaced
// by an in-register cross-lane bitonic merge within the wave: the 16
// per-query lists live in 16 lanes of one wave, so 4 levels of
// {u64 shfl_xor exchange, keep-min-16 via min(A[p],B[15-p]), 4-stage
// bitonic clean} produce the sorted team top-16 in lane 0.  LDS = 0,
// no __syncthreads.  256-thr blocks (16 teams) to stay within any
// per-CU workgroup limit -> 8 waves/SIMD launch-shape occupancy.
// Stop (R10): team-wide COUNT of candidates with d2 <= (r*s)^2 - eps;
// >=16 such proves union-16th <= Chebyshev bound (exact).
#define INSERTC(Af, OI)                                                      \
  {                                                                          \
    float dot = q.x * (Af).x;                                                \
    dot = fmaf(q.y, (Af).y, dot);                                            \
    dot = fmaf(q.z, (Af).z, dot);                                            \
    float d2 = (qsq + (Af).w) - 2.0f * dot;                                  \
    unsigned u = __float_as_uint(d2);                                        \
    u ^= (0x80000000u | (unsigned)((int)u >> 31));                           \
    u64 key = ((u64)u << 32) | (OI);                                         \
    if (key < lst[15]) {                                                     \
      u64 x = key;                                                           \
      _Pragma("unroll") for (int p = 0; p < 16; ++p) {                       \
        bool sw = x < lst[p];                                                \
        u64 a = lst[p];                                                      \
        lst[p] = sw ? x : a;                                                 \
        x = sw ? a : x;                                                      \
      }                                                                      \
    }                                                                        \
  }

#define SCANSEG(S0, S1)                                                      \
  {                                                                          \
    int j = (S0) + l;                                                        \
    for (; j + 16 < (S1); j += 32) {                                         \
      float4 A0 = sp[j];                                                     \
      unsigned o0 = sx[j];                                                   \
      float4 A1 = sp[j + 16];                                                \
      unsigned o1 = sx[j + 16];                                              \
      INSERTC(A0, o0)                                                        \
      INSERTC(A1, o1)                                                        \
    }                                                                        \
    if (j < (S1)) {                                                          \
      float4 A0 = sp[j];                                                     \
      unsigned o0 = sx[j];                                                   \
      INSERTC(A0, o0)                                                        \
    }                                                                        \
  }

#define CSWAP(ia, ib)                                                        \
  {                                                                          \
    u64 ta = c[ia], tb2 = c[ib];                                             \
    bool sw = ta > tb2;                                                      \
    c[ia] = sw ? tb2 : ta;                                                   \
    c[ib] = sw ? ta : tb2;                                                   \
  }

__global__ __launch_bounds__(256) void k_query(const float4* __restrict__ spts,
                                               const u16* __restrict__ sidx,
                                               const int* __restrict__ offs,
                                               const float* __restrict__ gp,
                                               u16* __restrict__ oidx) {
  const int tid = threadIdx.x;
  const int l = tid & 15;       // team lane
  const int team = tid >> 4;    // 0..15 (query within block)
  const int lane = tid & 63;    // wave lane
  const int qid = blockIdx.x * 16 + team;
  const int b = qid >> 13, i = qid & 8191;
  const float4* __restrict__ sp = spts + (b << 13);
  const u16* __restrict__ sx = sidx + (b << 13);
  const int* __restrict__ ob = offs + b * NCELLP;
  const float* g = gp + b * 8;
  float4 q = sp[i];
  const float qsq = q.w;  // sq precomputed
  const unsigned orig = sx[i];
  const int cx = cellof(q.x, g[0], g[4]);
  const int cy = cellof(q.y, g[1], g[4]);
  const int cz = cellof(q.z, g[2], g[4]);
  const float s = g[3];

  u64 lst[16];
#pragma unroll
  for (int p = 0; p < 16; ++p) lst[p] = ~0ULL;

  const int tb = lane & 48;  // team base within wave

  for (int r = 0; r <= GRID; ++r) {
    const int W = 2 * r + 1;
    const int nent = 2 * W * W;
    for (int base = 0; base < nent; base += 16) {
      // phase A: each lane loads bounds of its own entry (parallel chains)
      int ms0 = 0, ms1 = 0;
      const int eid = base + l;
      if (eid < nent) {
        const int rid = eid >> 1, side = eid & 1;
        const int dz = rid / W - r;
        const int dy = rid % W - r;
        const int z2 = cz + dz, y2 = cy + dy;
        if ((unsigned)z2 < GRID && (unsigned)y2 < GRID) {
          const int rowb = (z2 * GRID + y2) * GRID;
          const bool bdry = (dz == -r) || (dz == r) || (dy == -r) || (dy == r);
          if (bdry) {
            if (side == 0) {
              const int xl = cx - r < 0 ? 0 : cx - r;
              const int xh = cx + r > GRID - 1 ? GRID - 1 : cx + r;
              ms0 = ob[rowb + xl];
              ms1 = ob[rowb + xh + 1];
            }
          } else {
            const int x2 = side ? cx + r : cx - r;
            if ((unsigned)x2 < GRID) {
              ms0 = ob[rowb + x2];
              ms1 = ob[rowb + x2 + 1];
            }
          }
        }
      }
      // phase B: ballot-compact non-empty segments, broadcast, scan
      unsigned m = (unsigned)((__ballot(ms1 > ms0) >> tb) & 0xFFFFull);
      while (m) {
        const int e = __ffs(m) - 1;
        m &= m - 1;
        const int s0 = __shfl(ms0, tb + e);
        const int s1 = __shfl(ms1, tb + e);
        SCANSEG(s0, s1)
      }
    }
    // team stop check (R10): count team candidates with d2 <= (r*s)^2 - eps.
    const float rs = (float)r * s;
    const float T = fmaf(rs, rs, -1e-4f);
    unsigned tu = __float_as_uint(T);
    tu ^= (0x80000000u | (unsigned)((int)tu >> 31));
    int c = 0;
#pragma unroll
    for (int p = 0; p < 16; ++p) c += ((unsigned)(lst[p] >> 32) <= tu) ? 1 : 0;
    c += __shfl_xor(c, 1);
    c += __shfl_xor(c, 2);
    c += __shfl_xor(c, 4);
    c += __shfl_xor(c, 8);
    if (c >= 16) break;
  }

  // ---- in-register cross-lane merge (4 bitonic levels within team) ----
  // Level m: lane pair (l, l^m); keep-min lanes ((l&m)==0) take the 16
  // smallest of the 32 via min(A[p], B[15-p]) (bitonic), keep-max lanes
  // take the complement (kept sorted so later levels stay valid).
#pragma unroll
  for (int mm = 1; mm <= 8; mm <<= 1) {
    u64 c[16];
    const bool keepmin = (l & mm) == 0;
#pragma unroll
    for (int p = 0; p < 16; ++p) {
      u64 o = __shfl_xor(lst[15 - p], mm);
      u64 a = lst[p];
      u64 lo = a < o ? a : o;
      u64 hi = a < o ? o : a;
      c[p] = keepmin ? lo : hi;
    }
    // bitonic clean, ascending, distances 8,4,2,1 (compile-time indices)
    CSWAP(0, 8) CSWAP(1, 9) CSWAP(2, 10) CSWAP(3, 11)
    CSWAP(4, 12) CSWAP(5, 13) CSWAP(6, 14) CSWAP(7, 15)
    CSWAP(0, 4) CSWAP(1, 5) CSWAP(2, 6) CSWAP(3, 7)
    CSWAP(8, 12) CSWAP(9, 13) CSWAP(10, 14) CSWAP(11, 15)
    CSWAP(0, 2) CSWAP(1, 3) CSWAP(4, 6) CSWAP(5, 7)
    CSWAP(8, 10) CSWAP(9, 11) CSWAP(12, 14) CSWAP(13, 15)
    CSWAP(0, 1) CSWAP(2, 3) CSWAP(4, 5) CSWAP(6, 7)
    CSWAP(8, 9) CSWAP(10, 11) CSWAP(12, 13) CSWAP(14, 15)
#pragma unroll
    for (int p = 0; p < 16; ++p) lst[p] = c[p];
  }

  if (l == 0) {  // lane 0 of each team holds the sorted team top-16
    unsigned pk[8];
#pragma unroll
    for (int k = 0; k < 16; k += 2)
      pk[k >> 1] = (unsigned)(lst[k] & 0xFFFFull) |
                   ((unsigned)(lst[k + 1] & 0xFFFFull) << 16);
    unsigned* od = (unsigned*)(oidx + (((size_t)(b << 13) + orig) << 4));
#pragma unroll
    for (int k = 0; k < 8; ++k) od[k] = pk[k];
  }
}

// ---------------------------------------------------------------- K6: lt = feat @ lt_w + lt_b
__global__ __launch_bounds__(256) void k_lt(const float* __restrict__ feat,
                                            const float* __restrict__ ltw,
                                            const float* __restrict__ ltb,
                                            float* __restrict__ lt) {
  __shared__ float sw[64][196];
  __shared__ float sf[32][68];
  const int tid = threadIdx.x;
  const int r0 = blockIdx.x * 32;
#pragma unroll
  for (int i = 0; i < 12; ++i) {
    int v = tid + i * 256;
    float4 w4 = ((const float4*)ltw)[v];
    int row = (v * 4) / 192, col = (v * 4) % 192;
    *(float4*)&sw[row][col] = w4;
  }
#pragma unroll
  for (int i = 0; i < 2; ++i) {
    int v = tid + i * 256;
    int row = v >> 4, c4 = v & 15;
    float4 f4 = ((const float4*)(feat + (size_t)(r0 + row) * 64))[c4];
    *(float4*)&sf[row][c4 * 4] = f4;
  }
  __syncthreads();
  const int r = tid >> 3;
  const int c0 = (tid & 7) * 24;
  float acc[24];
#pragma unroll
  for (int ll = 0; ll < 24; ++ll) acc[ll] = ltb[c0 + ll];
#pragma unroll 4
  for (int j = 0; j < 64; ++j) {
    float f = sf[r][j];
#pragma unroll
    for (int l4 = 0; l4 < 6; ++l4) {
      float4 w4 = *(const float4*)&sw[j][c0 + l4 * 4];
      acc[l4 * 4 + 0] = fmaf(f, w4.x, acc[l4 * 4 + 0]);
      acc[l4 * 4 + 1] = fmaf(f, w4.y, acc[l4 * 4 + 1]);
      acc[l4 * 4 + 2] = fmaf(f, w4.z, acc[l4 * 4 + 2]);
      acc[l4 * 4 + 3] = fmaf(f, w4.w, acc[l4 * 4 + 3]);
    }
  }
  float* orow = lt + (size_t)(r0 + r) * 192 + c0;
#pragma unroll
  for (int l4 = 0; l4 < 6; ++l4)
    *(float4*)&orow[l4 * 4] = make_float4(acc[l4 * 4], acc[l4 * 4 + 1],
                                          acc[l4 * 4 + 2], acc[l4 * 4 + 3]);
}

// ---------------------------------------------------------------- K7: main
// R12: online softmax (no pre/apd/xk arrays), prefetch-1 psi/alp gathers,
// DPP+readlane LN reductions (VALU pipe) instead of __shfl_xor (DS pipe).
// DPP ctrl must be a compile-time constant -> template parameter.
template <int CTRL>
__device__ __forceinline__ float dpp_add_f(float x) {
  int y = __builtin_amdgcn_update_dpp(0, __float_as_int(x), CTRL, 0xf, 0xf,
                                      true);
  return x + __int_as_float(y);
}
// full-wave (64-lane) sum -> wave-uniform via readlane 63.
// row_shr 1/2/4/8: lane15 of each row16 = row sum; row_bcast:15 add:
// lane31 = rows0+1, lane63 = rows2+3; row_bcast:31 add: lane63 = total.
__device__ __forceinline__ float wave_sum64(float x) {
  x = dpp_add_f<0x111>(x);  // row_shr:1
  x = dpp_add_f<0x112>(x);  // row_shr:2
  x = dpp_add_f<0x114>(x);  // row_shr:4
  x = dpp_add_f<0x118>(x);  // row_shr:8
  x = dpp_add_f<0x142>(x);  // row_bcast:15
  x = dpp_add_f<0x143>(x);  // row_bcast:31
  return __int_as_float(__builtin_amdgcn_readlane(__float_as_int(x), 63));
}

__global__ __launch_bounds__(256) void k_main(
    const float4* __restrict__ xytp, const float* __restrict__ lt,
    const u16* __restrict__ knn, const float* __restrict__ pe_w1,
    const float* __restrict__ pe_b1, const float* __restrict__ pe_w2,
    const float* __restrict__ pe_b2, const float* __restrict__ ln_g,
    const float* __restrict__ ln_b, float* __restrict__ out) {
  __shared__ float s_h[4][16][64];
  const int lane = threadIdx.x & 63;
  const int wave = threadIdx.x >> 6;
  const int pid = __builtin_amdgcn_readfirstlane(blockIdx.x * 4 + wave);
  const int b = pid >> 13;
  const int n = pid & 8191;

  float w1c[4];
#pragma unroll
  for (int d = 0; d < 4; ++d) w1c[d] = pe_w1[d * 64 + lane];
  const float b1c = pe_b1[lane];
  float w2c[64];
#pragma unroll
  for (int j = 0; j < 64; ++j) w2c[j] = pe_w2[j * 64 + lane];
  const float b2c = pe_b2[lane];
  const float gc = ln_g[lane], bc = ln_b[lane];

  int nb[16];
#pragma unroll
  for (int k = 0; k < 16; ++k) nb[k] = knn[pid * 16 + k];

  const float* __restrict__ ltb = lt + (size_t)(b << 13) * 192;
  const float vc = ltb[(size_t)n * 192 + lane];

  const float4 qv = xytp[(b << 13) + n];
#pragma unroll
  for (int k = 0; k < 16; ++k) {
    float4 g = xytp[(b << 13) + nb[k]];
    float r0 = qv.x - g.x, r1 = qv.y - g.y, r2 = qv.z - g.z, r3 = qv.w - g.w;
    float h = fmaf(r3, w1c[3],
                   fmaf(r2, w1c[2], fmaf(r1, w1c[1], fmaf(r0, w1c[0], b1c))));
    s_h[wave][k][lane] = fmaxf(h, 0.0f);
  }
  __syncthreads();

  float psi_c = ltb[(size_t)nb[0] * 192 + 64 + lane];
  float alp_c = ltb[(size_t)nb[0] * 192 + 128 + lane];
  float m = -INFINITY, se = 0.f, oacc = 0.f;
#pragma unroll
  for (int k = 0; k < 16; ++k) {
    float psi_n = 0.f, alp_n = 0.f;
    if (k < 15) {  // prefetch next neighbor's psi/alp (distance-1)
      const float* row = ltb + (size_t)nb[k + 1] * 192;
      psi_n = row[64 + lane];
      alp_n = row[128 + lane];
    }
    float acc = b2c;
#pragma unroll
    for (int j4 = 0; j4 < 16; ++j4) {
      float4 h4 = *(const float4*)&s_h[wave][k][j4 * 4];
      acc = fmaf(h4.x, w2c[j4 * 4 + 0], acc);
      acc = fmaf(h4.y, w2c[j4 * 4 + 1], acc);
      acc = fmaf(h4.z, w2c[j4 * 4 + 2], acc);
      acc = fmaf(h4.w, w2c[j4 * 4 + 3], acc);
    }
    const float pre = (vc - psi_c) + acc;
    const float apd = alp_c + acc;
    const float sm = wave_sum64(pre);
    const float ssm = wave_sum64(pre * pre);
    const float mu = sm * 0.015625f;
    const float var = fmaf(ssm, 0.015625f, -mu * mu);
    const float inv = rsqrtf(var + 1e-5f);
    const float x = fmaf((pre - mu) * inv, gc, bc) * 0.125f;
    // online softmax update (first iter: m=-inf -> corr = exp(-inf) = 0)
    const float mn = fmaxf(m, x);
    const float corr = __expf(m - mn);
    const float e = __expf(x - mn);
    se = fmaf(se, corr, e);
    oacc = fmaf(oacc, corr, e * apd);
    m = mn;
    psi_c = psi_n;
    alp_c = alp_n;
  }
  out[(size_t)pid * 64 + lane] = oacc / se;
}

// ---------------------------------------------------------------- launch
extern "C" void kernel_launch(void* const* d_in, const int* in_sizes, int n_in,
                              void* d_out, int out_size, void* d_ws,
                              size_t ws_size, hipStream_t stream) {
  const float4* xytp = (const float4*)d_in[0];
  const float* features = (const float*)d_in[1];
  const float* pe_w1 = (const float*)d_in[2];
  const float* pe_b1 = (const float*)d_in[3];
  const float* pe_w2 = (const float*)d_in[4];
  const float* pe_b2 = (const float*)d_in[5];
  const float* lt_w = (const float*)d_in[6];
  const float* lt_b = (const float*)d_in[7];
  const float* ln_g = (const float*)d_in[8];
  const float* ln_b = (const float*)d_in[9];
  float* out = (float*)d_out;

  char* ws = (char*)d_ws;
  u16* idxbuf = (u16*)(ws + WS_IDX);
  float* lt = (float*)(ws + WS_LT);
  int* cnt = (int*)(ws + WS_CNT);
  int* offs = (int*)(ws + WS_OFF);
  int* curs = (int*)(ws + WS_CUR);
  float4* spts = (float4*)(ws + WS_SP);
  float* gp = (float*)(ws + WS_GP);
  u16* sidx = (u16*)(ws + WS_SIDX);

  k_minmax<<<BATCH, 256, 0, stream>>>(xytp, gp, cnt);
  k_count<<<(BATCH * NPTS) / 256, 256, 0, stream>>>(xytp, gp, cnt);
  k_scan<<<BATCH, 1024, 0, stream>>>(cnt, offs, curs);
  k_scatter<<<(BATCH * NPTS) / 256, 256, 0, stream>>>(xytp, gp, curs, spts,
                                                      sidx);
  k_query<<<(BATCH * NPTS) / 16, 256, 0, stream>>>(spts, sidx, offs, gp,
                                                   idxbuf);
  k_lt<<<(BATCH * NPTS) / 32, 256, 0, stream>>>(features, lt_w, lt_b, lt);
  k_main<<<(BATCH * NPTS) / 4, 256, 0, stream>>>(xytp, lt, idxbuf, pe_w1,
                                                 pe_b1, pe_w2, pe_b2, ln_g,
                                                 ln_b, out);
}

// Round 6
// 467.528 us; speedup vs baseline: 1.0491x; 1.0031x over previous
//
#include <hip/hip_runtime.h>
#include <stdint.h>

#define BATCH 4
#define NPTS 8192
#define KNN_K 16
#define GRID 24
#define NCELL (GRID * GRID * GRID)  // 13824
#define NCELLP (NCELL + 8)          // offs stride (sentinel slot)

typedef unsigned long long u64;
typedef unsigned short u16;

// ws layout (bytes)
#define WS_IDX 0u          // u16[4*8192*16]            = 1,048,576
#define WS_LT 1048576u     // float[4*8192*192]         = 25,165,824
#define WS_CNT 26214400u   // int[4*13824]              = 221,184
#define WS_OFF 26435584u   // int[4*13832]              = 221,312
#define WS_CUR 26656896u   // int[4*13824]              = 221,184
#define WS_SP 26878080u    // float4[4*8192]            = 524,288
#define WS_GP 27402368u    // float[4*8]                = 128
#define WS_SIDX 27402496u  // u16[4*8192]               = 65,536

__device__ __forceinline__ int cellof(float v, float o, float invs) {
  int c = (int)((v - o) * invs);
  return c < GRID - 1 ? c : GRID - 1;
}

// ---------------------------------------------------------------- K0: bbox + zero counters
__global__ __launch_bounds__(256) void k_minmax(const float4* __restrict__ xytp,
                                                float* __restrict__ gp,
                                                int* __restrict__ cnt) {
  const int b = blockIdx.x, t = threadIdx.x;
  for (int c = t; c < NCELL; c += 256) cnt[b * NCELL + c] = 0;
  const float4* pb = xytp + (b << 13);
  float mnx = INFINITY, mny = INFINITY, mnz = INFINITY;
  float mxx = -INFINITY, mxy = -INFINITY, mxz = -INFINITY;
  for (int i = t; i < NPTS; i += 256) {
    float4 p = pb[i];
    mnx = fminf(mnx, p.x); mny = fminf(mny, p.y); mnz = fminf(mnz, p.z);
    mxx = fmaxf(mxx, p.x); mxy = fmaxf(mxy, p.y); mxz = fmaxf(mxz, p.z);
  }
#pragma unroll
  for (int d = 1; d < 64; d <<= 1) {
    mnx = fminf(mnx, __shfl_xor(mnx, d)); mny = fminf(mny, __shfl_xor(mny, d));
    mnz = fminf(mnz, __shfl_xor(mnz, d)); mxx = fmaxf(mxx, __shfl_xor(mxx, d));
    mxy = fmaxf(mxy, __shfl_xor(mxy, d)); mxz = fmaxf(mxz, __shfl_xor(mxz, d));
  }
  __shared__ float red[4][6];
  const int lane = t & 63, wv = t >> 6;
  if (lane == 0) {
    red[wv][0] = mnx; red[wv][1] = mny; red[wv][2] = mnz;
    red[wv][3] = mxx; red[wv][4] = mxy; red[wv][5] = mxz;
  }
  __syncthreads();
  if (t == 0) {
    for (int w = 1; w < 4; ++w) {
      red[0][0] = fminf(red[0][0], red[w][0]);
      red[0][1] = fminf(red[0][1], red[w][1]);
      red[0][2] = fminf(red[0][2], red[w][2]);
      red[0][3] = fmaxf(red[0][3], red[w][3]);
      red[0][4] = fmaxf(red[0][4], red[w][4]);
      red[0][5] = fmaxf(red[0][5], red[w][5]);
    }
    float rmax = fmaxf(red[0][3] - red[0][0],
                       fmaxf(red[0][4] - red[0][1], red[0][5] - red[0][2]));
    float s = rmax / (float)GRID;
    float* g = gp + b * 8;
    g[0] = red[0][0]; g[1] = red[0][1]; g[2] = red[0][2];
    g[3] = s; g[4] = 1.0f / s;
  }
}

// ---------------------------------------------------------------- K2: count
__global__ __launch_bounds__(256) void k_count(const float4* __restrict__ xytp,
                                               const float* __restrict__ gp,
                                               int* __restrict__ cnt) {
  int i = blockIdx.x * 256 + threadIdx.x;
  int b = i >> 13;
  const float* g = gp + b * 8;
  float4 p = xytp[i];
  int cx = cellof(p.x, g[0], g[4]);
  int cy = cellof(p.y, g[1], g[4]);
  int cz = cellof(p.z, g[2], g[4]);
  atomicAdd(&cnt[b * NCELL + (cz * GRID + cy) * GRID + cx], 1);
}

// ---------------------------------------------------------------- K3: exclusive scan
// offs has stride NCELLP with offs[b*NCELLP + NCELL] = NPTS sentinel, so
// end(cell c) == offs[c+1] works for every cell including the last.
__global__ __launch_bounds__(1024) void k_scan(const int* __restrict__ cnt,
                                               int* __restrict__ offs,
                                               int* __restrict__ curs) {
  __shared__ int wsum[16];
  const int b = blockIdx.x, t = threadIdx.x;
  const int base = b * NCELL;
  const int base2 = b * NCELLP;
  const int lo = t * 14;
  const int hi = lo + 14 < NCELL ? lo + 14 : NCELL;
  int s = 0;
  for (int c = lo; c < hi; ++c) s += cnt[base + c];
  const int lane = t & 63, wv = t >> 6;
  int v = s;
#pragma unroll
  for (int d = 1; d < 64; d <<= 1) {
    int u = __shfl_up(v, d);
    if (lane >= d) v += u;
  }
  if (lane == 63) wsum[wv] = v;
  __syncthreads();
  if (wv == 0 && lane < 16) {
    int x = wsum[lane];
#pragma unroll
    for (int d = 1; d < 16; d <<= 1) {
      int u = __shfl_up(x, d, 16);
      if (lane >= d) x += u;
    }
    wsum[lane] = x;
  }
  __syncthreads();
  int excl = (wv > 0 ? wsum[wv - 1] : 0) + v - s;
  for (int c = lo; c < hi; ++c) {
    offs[base2 + c] = excl;
    curs[base + c] = excl;
    excl += cnt[base + c];
  }
  if (hi == NCELL) offs[base2 + NCELL] = excl;  // == NPTS
}

// ---------------------------------------------------------------- K4: scatter (cell-sorted points, sq in .w, idx in sidx)
__global__ __launch_bounds__(256) void k_scatter(const float4* __restrict__ xytp,
                                                 const float* __restrict__ gp,
                                                 int* __restrict__ curs,
                                                 float4* __restrict__ spts,
                                                 u16* __restrict__ sidx) {
  int i = blockIdx.x * 256 + threadIdx.x;
  int b = i >> 13, n = i & 8191;
  const float* g = gp + b * 8;
  float4 p = xytp[i];
  int cx = cellof(p.x, g[0], g[4]);
  int cy = cellof(p.y, g[1], g[4]);
  int cz = cellof(p.z, g[2], g[4]);
  int pos = atomicAdd(&curs[b * NCELL + (cz * GRID + cy) * GRID + cx], 1);
  float sq = fmaf(p.z, p.z, fmaf(p.y, p.y, p.x * p.x));
  spts[(b << 13) + pos] = make_float4(p.x, p.y, p.z, sq);
  sidx[(b << 13) + pos] = (u16)n;
}

// ---------------------------------------------------------------- K5: grid KNN query
// R15: phase-A loads HOISTED.  R5 post-mortem: grid == exactly one
// full-chip residency, no refill; time-avg occupancy 5.3/32 waves/CU
// -> makespan ~6x mean wave time, dominated by sparse queries whose
// shells serialize ~nent/16 dependent-L2-load rounds.  Now bounds
// loads for 128 entries (8 pairs/lane) are issued back-to-back into
// registers (independent -> all in flight, one latency round per 128
// entries), then the 8 ballot+scan groups consume them in order.
// Enumeration / INSERTC / count-stop / bitonic merge unchanged (R14).
#define INSERTC(Af, OI)                                                      \
  {                                                                          \
    float dot = q.x * (Af).x;                                                \
    dot = fmaf(q.y, (Af).y, dot);                                            \
    dot = fmaf(q.z, (Af).z, dot);                                            \
    float d2 = (qsq + (Af).w) - 2.0f * dot;                                  \
    unsigned u = __float_as_uint(d2);                                        \
    u ^= (0x80000000u | (unsigned)((int)u >> 31));                           \
    u64 key = ((u64)u << 32) | (OI);                                         \
    if (key < lst[15]) {                                                     \
      u64 x = key;                                                           \
      _Pragma("unroll") for (int p = 0; p < 16; ++p) {                       \
        bool sw = x < lst[p];                                                \
        u64 a = lst[p];                                                      \
        lst[p] = sw ? x : a;                                                 \
        x = sw ? a : x;                                                      \
      }                                                                      \
    }                                                                        \
  }

#define SCANSEG(S0, S1)                                                      \
  {                                                                          \
    int j = (S0) + l;                                                        \
    for (; j + 16 < (S1); j += 32) {                                         \
      float4 A0 = sp[j];                                                     \
      unsigned o0 = sx[j];                                                   \
      float4 A1 = sp[j + 16];                                                \
      unsigned o1 = sx[j + 16];                                              \
      INSERTC(A0, o0)                                                        \
      INSERTC(A1, o1)                                                        \
    }                                                                        \
    if (j < (S1)) {                                                          \
      float4 A0 = sp[j];                                                     \
      unsigned o0 = sx[j];                                                   \
      INSERTC(A0, o0)                                                        \
    }                                                                        \
  }

#define CSWAP(ia, ib)                                                        \
  {                                                                          \
    u64 ta = c[ia], tb2 = c[ib];                                             \
    bool sw = ta > tb2;                                                      \
    c[ia] = sw ? tb2 : ta;                                                   \
    c[ib] = sw ? ta : tb2;                                                   \
  }

#define QCHUNK 8  // entry pairs per lane hoisted per round (128 entries)

__global__ __launch_bounds__(256) void k_query(const float4* __restrict__ spts,
                                               const u16* __restrict__ sidx,
                                               const int* __restrict__ offs,
                                               const float* __restrict__ gp,
                                               u16* __restrict__ oidx) {
  const int tid = threadIdx.x;
  const int l = tid & 15;       // team lane
  const int team = tid >> 4;    // 0..15 (query within block)
  const int lane = tid & 63;    // wave lane
  const int qid = blockIdx.x * 16 + team;
  const int b = qid >> 13, i = qid & 8191;
  const float4* __restrict__ sp = spts + (b << 13);
  const u16* __restrict__ sx = sidx + (b << 13);
  const int* __restrict__ ob = offs + b * NCELLP;
  const float* g = gp + b * 8;
  float4 q = sp[i];
  const float qsq = q.w;  // sq precomputed
  const unsigned orig = sx[i];
  const int cx = cellof(q.x, g[0], g[4]);
  const int cy = cellof(q.y, g[1], g[4]);
  const int cz = cellof(q.z, g[2], g[4]);
  const float s = g[3];

  u64 lst[16];
#pragma unroll
  for (int p = 0; p < 16; ++p) lst[p] = ~0ULL;

  const int tb = lane & 48;  // team base within wave

  for (int r = 0; r <= GRID; ++r) {
    const int W = 2 * r + 1;
    const int nent = 2 * W * W;
    for (int cb = 0; cb < nent; cb += 16 * QCHUNK) {
      int ms0[QCHUNK], ms1[QCHUNK];
      // phase A (hoisted): issue all bounds loads for this chunk; the
      // 2*QCHUNK loads per lane are independent -> single latency round.
#pragma unroll
      for (int u2 = 0; u2 < QCHUNK; ++u2) {
        ms0[u2] = 0; ms1[u2] = 0;
        const int eid = cb + u2 * 16 + l;
        if (eid < nent) {
          const int rid = eid >> 1, side = eid & 1;
          const int dz = rid / W - r;
          const int dy = rid % W - r;
          const int z2 = cz + dz, y2 = cy + dy;
          if ((unsigned)z2 < GRID && (unsigned)y2 < GRID) {
            const int rowb = (z2 * GRID + y2) * GRID;
            const bool bdry = (dz == -r) || (dz == r) || (dy == -r) || (dy == r);
            if (bdry) {
              if (side == 0) {
                const int xl = cx - r < 0 ? 0 : cx - r;
                const int xh = cx + r > GRID - 1 ? GRID - 1 : cx + r;
                ms0[u2] = ob[rowb + xl];
                ms1[u2] = ob[rowb + xh + 1];
              }
            } else {
              const int x2 = side ? cx + r : cx - r;
              if ((unsigned)x2 < GRID) {
                ms0[u2] = ob[rowb + x2];
                ms1[u2] = ob[rowb + x2 + 1];
              }
            }
          }
        }
      }
      // phase B: ballot-compact non-empty segments per 16-entry group
#pragma unroll
      for (int u2 = 0; u2 < QCHUNK; ++u2) {
        unsigned m = (unsigned)((__ballot(ms1[u2] > ms0[u2]) >> tb) & 0xFFFFull);
        while (m) {
          const int e = __ffs(m) - 1;
          m &= m - 1;
          const int s0 = __shfl(ms0[u2], tb + e);
          const int s1 = __shfl(ms1[u2], tb + e);
          SCANSEG(s0, s1)
        }
      }
    }
    // team stop check (R10): count team candidates with d2 <= (r*s)^2 - eps.
    const float rs = (float)r * s;
    const float T = fmaf(rs, rs, -1e-4f);
    unsigned tu = __float_as_uint(T);
    tu ^= (0x80000000u | (unsigned)((int)tu >> 31));
    int c = 0;
#pragma unroll
    for (int p = 0; p < 16; ++p) c += ((unsigned)(lst[p] >> 32) <= tu) ? 1 : 0;
    c += __shfl_xor(c, 1);
    c += __shfl_xor(c, 2);
    c += __shfl_xor(c, 4);
    c += __shfl_xor(c, 8);
    if (c >= 16) break;
  }

  // ---- in-register cross-lane merge (4 bitonic levels within team) ----
#pragma unroll
  for (int mm = 1; mm <= 8; mm <<= 1) {
    u64 c[16];
    const bool keepmin = (l & mm) == 0;
#pragma unroll
    for (int p = 0; p < 16; ++p) {
      u64 o = __shfl_xor(lst[15 - p], mm);
      u64 a = lst[p];
      u64 lo = a < o ? a : o;
      u64 hi = a < o ? o : a;
      c[p] = keepmin ? lo : hi;
    }
    CSWAP(0, 8) CSWAP(1, 9) CSWAP(2, 10) CSWAP(3, 11)
    CSWAP(4, 12) CSWAP(5, 13) CSWAP(6, 14) CSWAP(7, 15)
    CSWAP(0, 4) CSWAP(1, 5) CSWAP(2, 6) CSWAP(3, 7)
    CSWAP(8, 12) CSWAP(9, 13) CSWAP(10, 14) CSWAP(11, 15)
    CSWAP(0, 2) CSWAP(1, 3) CSWAP(4, 6) CSWAP(5, 7)
    CSWAP(8, 10) CSWAP(9, 11) CSWAP(12, 14) CSWAP(13, 15)
    CSWAP(0, 1) CSWAP(2, 3) CSWAP(4, 5) CSWAP(6, 7)
    CSWAP(8, 9) CSWAP(10, 11) CSWAP(12, 13) CSWAP(14, 15)
#pragma unroll
    for (int p = 0; p < 16; ++p) lst[p] = c[p];
  }

  if (l == 0) {  // lane 0 of each team holds the sorted team top-16
    unsigned pk[8];
#pragma unroll
    for (int k = 0; k < 16; k += 2)
      pk[k >> 1] = (unsigned)(lst[k] & 0xFFFFull) |
                   ((unsigned)(lst[k + 1] & 0xFFFFull) << 16);
    unsigned* od = (unsigned*)(oidx + (((size_t)(b << 13) + orig) << 4));
#pragma unroll
    for (int k = 0; k < 8; ++k) od[k] = pk[k];
  }
}

// ---------------------------------------------------------------- K6: lt = feat @ lt_w + lt_b
__global__ __launch_bounds__(256) void k_lt(const float* __restrict__ feat,
                                            const float* __restrict__ ltw,
                                            const float* __restrict__ ltb,
                                            float* __restrict__ lt) {
  __shared__ float sw[64][196];
  __shared__ float sf[32][68];
  const int tid = threadIdx.x;
  const int r0 = blockIdx.x * 32;
#pragma unroll
  for (int i = 0; i < 12; ++i) {
    int v = tid + i * 256;
    float4 w4 = ((const float4*)ltw)[v];
    int row = (v * 4) / 192, col = (v * 4) % 192;
    *(float4*)&sw[row][col] = w4;
  }
#pragma unroll
  for (int i = 0; i < 2; ++i) {
    int v = tid + i * 256;
    int row = v >> 4, c4 = v & 15;
    float4 f4 = ((const float4*)(feat + (size_t)(r0 + row) * 64))[c4];
    *(float4*)&sf[row][c4 * 4] = f4;
  }
  __syncthreads();
  const int r = tid >> 3;
  const int c0 = (tid & 7) * 24;
  float acc[24];
#pragma unroll
  for (int ll = 0; ll < 24; ++ll) acc[ll] = ltb[c0 + ll];
#pragma unroll 4
  for (int j = 0; j < 64; ++j) {
    float f = sf[r][j];
#pragma unroll
    for (int l4 = 0; l4 < 6; ++l4) {
      float4 w4 = *(const float4*)&sw[j][c0 + l4 * 4];
      acc[l4 * 4 + 0] = fmaf(f, w4.x, acc[l4 * 4 + 0]);
      acc[l4 * 4 + 1] = fmaf(f, w4.y, acc[l4 * 4 + 1]);
      acc[l4 * 4 + 2] = fmaf(f, w4.z, acc[l4 * 4 + 2]);
      acc[l4 * 4 + 3] = fmaf(f, w4.w, acc[l4 * 4 + 3]);
    }
  }
  float* orow = lt + (size_t)(r0 + r) * 192 + c0;
#pragma unroll
  for (int l4 = 0; l4 < 6; ++l4)
    *(float4*)&orow[l4 * 4] = make_float4(acc[l4 * 4], acc[l4 * 4 + 1],
                                          acc[l4 * 4 + 2], acc[l4 * 4 + 3]);
}

// ---------------------------------------------------------------- K7: main
// R12: online softmax (no pre/apd/xk arrays), prefetch-1 psi/alp gathers,
// DPP+readlane LN reductions (VALU pipe) instead of __shfl_xor (DS pipe).
// DPP ctrl must be a compile-time constant -> template parameter.
template <int CTRL>
__device__ __forceinline__ float dpp_add_f(float x) {
  int y = __builtin_amdgcn_update_dpp(0, __float_as_int(x), CTRL, 0xf, 0xf,
                                      true);
  return x + __int_as_float(y);
}
// full-wave (64-lane) sum -> wave-uniform via readlane 63.
// row_shr 1/2/4/8: lane15 of each row16 = row sum; row_bcast:15 add:
// lane31 = rows0+1, lane63 = rows2+3; row_bcast:31 add: lane63 = total.
__device__ __forceinline__ float wave_sum64(float x) {
  x = dpp_add_f<0x111>(x);  // row_shr:1
  x = dpp_add_f<0x112>(x);  // row_shr:2
  x = dpp_add_f<0x114>(x);  // row_shr:4
  x = dpp_add_f<0x118>(x);  // row_shr:8
  x = dpp_add_f<0x142>(x);  // row_bcast:15
  x = dpp_add_f<0x143>(x);  // row_bcast:31
  return __int_as_float(__builtin_amdgcn_readlane(__float_as_int(x), 63));
}

__global__ __launch_bounds__(256) void k_main(
    const float4* __restrict__ xytp, const float* __restrict__ lt,
    const u16* __restrict__ knn, const float* __restrict__ pe_w1,
    const float* __restrict__ pe_b1, const float* __restrict__ pe_w2,
    const float* __restrict__ pe_b2, const float* __restrict__ ln_g,
    const float* __restrict__ ln_b, float* __restrict__ out) {
  __shared__ float s_h[4][16][64];
  const int lane = threadIdx.x & 63;
  const int wave = threadIdx.x >> 6;
  const int pid = __builtin_amdgcn_readfirstlane(blockIdx.x * 4 + wave);
  const int b = pid >> 13;
  const int n = pid & 8191;

  float w1c[4];
#pragma unroll
  for (int d = 0; d < 4; ++d) w1c[d] = pe_w1[d * 64 + lane];
  const float b1c = pe_b1[lane];
  float w2c[64];
#pragma unroll
  for (int j = 0; j < 64; ++j) w2c[j] = pe_w2[j * 64 + lane];
  const float b2c = pe_b2[lane];
  const float gc = ln_g[lane], bc = ln_b[lane];

  int nb[16];
#pragma unroll
  for (int k = 0; k < 16; ++k) nb[k] = knn[pid * 16 + k];

  const float* __restrict__ ltb = lt + (size_t)(b << 13) * 192;
  const float vc = ltb[(size_t)n * 192 + lane];

  const float4 qv = xytp[(b << 13) + n];
#pragma unroll
  for (int k = 0; k < 16; ++k) {
    float4 g = xytp[(b << 13) + nb[k]];
    float r0 = qv.x - g.x, r1 = qv.y - g.y, r2 = qv.z - g.z, r3 = qv.w - g.w;
    float h = fmaf(r3, w1c[3],
                   fmaf(r2, w1c[2], fmaf(r1, w1c[1], fmaf(r0, w1c[0], b1c))));
    s_h[wave][k][lane] = fmaxf(h, 0.0f);
  }
  __syncthreads();

  float psi_c = ltb[(size_t)nb[0] * 192 + 64 + lane];
  float alp_c = ltb[(size_t)nb[0] * 192 + 128 + lane];
  float m = -INFINITY, se = 0.f, oacc = 0.f;
#pragma unroll
  for (int k = 0; k < 16; ++k) {
    float psi_n = 0.f, alp_n = 0.f;
    if (k < 15) {  // prefetch next neighbor's psi/alp (distance-1)
      const float* row = ltb + (size_t)nb[k + 1] * 192;
      psi_n = row[64 + lane];
      alp_n = row[128 + lane];
    }
    float acc = b2c;
#pragma unroll
    for (int j4 = 0; j4 < 16; ++j4) {
      float4 h4 = *(const float4*)&s_h[wave][k][j4 * 4];
      acc = fmaf(h4.x, w2c[j4 * 4 + 0], acc);
      acc = fmaf(h4.y, w2c[j4 * 4 + 1], acc);
      acc = fmaf(h4.z, w2c[j4 * 4 + 2], acc);
      acc = fmaf(h4.w, w2c[j4 * 4 + 3], acc);
    }
    const float pre = (vc - psi_c) + acc;
    const float apd = alp_c + acc;
    const float sm = wave_sum64(pre);
    const float ssm = wave_sum64(pre * pre);
    const float mu = sm * 0.015625f;
    const float var = fmaf(ssm, 0.015625f, -mu * mu);
    const float inv = rsqrtf(var + 1e-5f);
    const float x = fmaf((pre - mu) * inv, gc, bc) * 0.125f;
    // online softmax update (first iter: m=-inf -> corr = exp(-inf) = 0)
    const float mn = fmaxf(m, x);
    const float corr = __expf(m - mn);
    const float e = __expf(x - mn);
    se = fmaf(se, corr, e);
    oacc = fmaf(oacc, corr, e * apd);
    m = mn;
    psi_c = psi_n;
    alp_c = alp_n;
  }
  out[(size_t)pid * 64 + lane] = oacc / se;
}

// ---------------------------------------------------------------- launch
extern "C" void kernel_launch(void* const* d_in, const int* in_sizes, int n_in,
                              void* d_out, int out_size, void* d_ws,
                              size_t ws_size, hipStream_t stream) {
  const float4* xytp = (const float4*)d_in[0];
  const float* features = (const float*)d_in[1];
  const float* pe_w1 = (const float*)d_in[2];
  const float* pe_b1 = (const float*)d_in[3];
  const float* pe_w2 = (const float*)d_in[4];
  const float* pe_b2 = (const float*)d_in[5];
  const float* lt_w = (const float*)d_in[6];
  const float* lt_b = (const float*)d_in[7];
  const float* ln_g = (const float*)d_in[8];
  const float* ln_b = (const float*)d_in[9];
  float* out = (float*)d_out;

  char* ws = (char*)d_ws;
  u16* idxbuf = (u16*)(ws + WS_IDX);
  float* lt = (float*)(ws + WS_LT);
  int* cnt = (int*)(ws + WS_CNT);
  int* offs = (int*)(ws + WS_OFF);
  int* curs = (int*)(ws + WS_CUR);
  float4* spts = (float4*)(ws + WS_SP);
  float* gp = (float*)(ws + WS_GP);
  u16* sidx = (u16*)(ws + WS_SIDX);

  k_minmax<<<BATCH, 256, 0, stream>>>(xytp, gp, cnt);
  k_count<<<(BATCH * NPTS) / 256, 256, 0, stream>>>(xytp, gp, cnt);
  k_scan<<<BATCH, 1024, 0, stream>>>(cnt, offs, curs);
  k_scatter<<<(BATCH * NPTS) / 256, 256, 0, stream>>>(xytp, gp, curs, spts,
                                                      sidx);
  k_query<<<(BATCH * NPTS) / 16, 256, 0, stream>>>(spts, sidx, offs, gp,
                                                   idxbuf);
  k_lt<<<(BATCH * NPTS) / 32, 256, 0, stream>>>(features, lt_w, lt_b, lt);
  k_main<<<(BATCH * NPTS) / 4, 256, 0, stream>>>(xytp, lt, idxbuf, pe_w1,
                                                 pe_b1, pe_w2, pe_b2, ln_g,
                                                 ln_b, out);
}

// Round 7
// 450.359 us; speedup vs baseline: 1.0891x; 1.0381x over previous
//
#include <hip/hip_runtime.h>
#include <stdint.h>

#define BATCH 4
#define NPTS 8192
#define KNN_K 16
#define GRID 24
#define NCELL (GRID * GRID * GRID)  // 13824
#define NCELLP (NCELL + 8)          // offs stride (sentinel slot)

typedef unsigned long long u64;
typedef unsigned short u16;

// ws layout (bytes)
#define WS_IDX 0u          // u16[4*8192*16]            = 1,048,576
#define WS_LT 1048576u     // float[4*8192*192]         = 25,165,824
#define WS_CNT 26214400u   // int[4*13824]              = 221,184
#define WS_OFF 26435584u   // int[4*13832]              = 221,312
#define WS_CUR 26656896u   // int[4*13824]              = 221,184
#define WS_SP 26878080u    // float4[4*8192]            = 524,288
#define WS_GP 27402368u    // float[4*8]                = 128
#define WS_SIDX 27402496u  // u16[4*8192]               = 65,536

__device__ __forceinline__ int cellof(float v, float o, float invs) {
  int c = (int)((v - o) * invs);
  return c < GRID - 1 ? c : GRID - 1;
}

// ---------------------------------------------------------------- K0: bbox + zero counters
__global__ __launch_bounds__(256) void k_minmax(const float4* __restrict__ xytp,
                                                float* __restrict__ gp,
                                                int* __restrict__ cnt) {
  const int b = blockIdx.x, t = threadIdx.x;
  for (int c = t; c < NCELL; c += 256) cnt[b * NCELL + c] = 0;
  const float4* pb = xytp + (b << 13);
  float mnx = INFINITY, mny = INFINITY, mnz = INFINITY;
  float mxx = -INFINITY, mxy = -INFINITY, mxz = -INFINITY;
  for (int i = t; i < NPTS; i += 256) {
    float4 p = pb[i];
    mnx = fminf(mnx, p.x); mny = fminf(mny, p.y); mnz = fminf(mnz, p.z);
    mxx = fmaxf(mxx, p.x); mxy = fmaxf(mxy, p.y); mxz = fmaxf(mxz, p.z);
  }
#pragma unroll
  for (int d = 1; d < 64; d <<= 1) {
    mnx = fminf(mnx, __shfl_xor(mnx, d)); mny = fminf(mny, __shfl_xor(mny, d));
    mnz = fminf(mnz, __shfl_xor(mnz, d)); mxx = fmaxf(mxx, __shfl_xor(mxx, d));
    mxy = fmaxf(mxy, __shfl_xor(mxy, d)); mxz = fmaxf(mxz, __shfl_xor(mxz, d));
  }
  __shared__ float red[4][6];
  const int lane = t & 63, wv = t >> 6;
  if (lane == 0) {
    red[wv][0] = mnx; red[wv][1] = mny; red[wv][2] = mnz;
    red[wv][3] = mxx; red[wv][4] = mxy; red[wv][5] = mxz;
  }
  __syncthreads();
  if (t == 0) {
    for (int w = 1; w < 4; ++w) {
      red[0][0] = fminf(red[0][0], red[w][0]);
      red[0][1] = fminf(red[0][1], red[w][1]);
      red[0][2] = fminf(red[0][2], red[w][2]);
      red[0][3] = fmaxf(red[0][3], red[w][3]);
      red[0][4] = fmaxf(red[0][4], red[w][4]);
      red[0][5] = fmaxf(red[0][5], red[w][5]);
    }
    float rmax = fmaxf(red[0][3] - red[0][0],
                       fmaxf(red[0][4] - red[0][1], red[0][5] - red[0][2]));
    float s = rmax / (float)GRID;
    float* g = gp + b * 8;
    g[0] = red[0][0]; g[1] = red[0][1]; g[2] = red[0][2];
    g[3] = s; g[4] = 1.0f / s;
  }
}

// ---------------------------------------------------------------- K2: count
__global__ __launch_bounds__(256) void k_count(const float4* __restrict__ xytp,
                                               const float* __restrict__ gp,
                                               int* __restrict__ cnt) {
  int i = blockIdx.x * 256 + threadIdx.x;
  int b = i >> 13;
  const float* g = gp + b * 8;
  float4 p = xytp[i];
  int cx = cellof(p.x, g[0], g[4]);
  int cy = cellof(p.y, g[1], g[4]);
  int cz = cellof(p.z, g[2], g[4]);
  atomicAdd(&cnt[b * NCELL + (cz * GRID + cy) * GRID + cx], 1);
}

// ---------------------------------------------------------------- K3: exclusive scan
// offs has stride NCELLP with offs[b*NCELLP + NCELL] = NPTS sentinel, so
// end(cell c) == offs[c+1] works for every cell including the last.
__global__ __launch_bounds__(1024) void k_scan(const int* __restrict__ cnt,
                                               int* __restrict__ offs,
                                               int* __restrict__ curs) {
  __shared__ int wsum[16];
  const int b = blockIdx.x, t = threadIdx.x;
  const int base = b * NCELL;
  const int base2 = b * NCELLP;
  const int lo = t * 14;
  const int hi = lo + 14 < NCELL ? lo + 14 : NCELL;
  int s = 0;
  for (int c = lo; c < hi; ++c) s += cnt[base + c];
  const int lane = t & 63, wv = t >> 6;
  int v = s;
#pragma unroll
  for (int d = 1; d < 64; d <<= 1) {
    int u = __shfl_up(v, d);
    if (lane >= d) v += u;
  }
  if (lane == 63) wsum[wv] = v;
  __syncthreads();
  if (wv == 0 && lane < 16) {
    int x = wsum[lane];
#pragma unroll
    for (int d = 1; d < 16; d <<= 1) {
      int u = __shfl_up(x, d, 16);
      if (lane >= d) x += u;
    }
    wsum[lane] = x;
  }
  __syncthreads();
  int excl = (wv > 0 ? wsum[wv - 1] : 0) + v - s;
  for (int c = lo; c < hi; ++c) {
    offs[base2 + c] = excl;
    curs[base + c] = excl;
    excl += cnt[base + c];
  }
  if (hi == NCELL) offs[base2 + NCELL] = excl;  // == NPTS
}

// ---------------------------------------------------------------- K4: scatter (cell-sorted points, sq in .w, idx in sidx)
__global__ __launch_bounds__(256) void k_scatter(const float4* __restrict__ xytp,
                                                 const float* __restrict__ gp,
                                                 int* __restrict__ curs,
                                                 float4* __restrict__ spts,
                                                 u16* __restrict__ sidx) {
  int i = blockIdx.x * 256 + threadIdx.x;
  int b = i >> 13, n = i & 8191;
  const float* g = gp + b * 8;
  float4 p = xytp[i];
  int cx = cellof(p.x, g[0], g[4]);
  int cy = cellof(p.y, g[1], g[4]);
  int cz = cellof(p.z, g[2], g[4]);
  int pos = atomicAdd(&curs[b * NCELL + (cz * GRID + cy) * GRID + cx], 1);
  float sq = fmaf(p.z, p.z, fmaf(p.y, p.y, p.x * p.x));
  spts[(b << 13) + pos] = make_float4(p.x, p.y, p.z, sq);
  sidx[(b << 13) + pos] = (u16)n;
}

// ---------------------------------------------------------------- K5: grid KNN query
// R16: within-batch segment CONCATENATION.  R6 post-mortem arithmetic:
// ~13k VALU instrs/wave; insert chain (~92 ops) fires per candidate-STEP
// (wave pays if ANY of 64 lanes inserts, P~1), so the lever is fewer
// steps.  Old dealing: stride-16 per cell segment (mean ~7 pts) -> one
// chain-step per segment at ~40% lane fill + ~8 ops ballot bookkeeping.
// Now: per 16-entry batch, prefix-sum the segment lengths (4 masked
// shfl_up), store {incl_prefix, start-excl_prefix} per segment in a
// per-team LDS int2[16] (2KB/block), and deal the FLATTENED candidate
// range vidx=l,l+16,..<total; each lane resolves its segment via a
// cached-bound LDS advance (lane-local; no cross-lane ops inside any
// divergent region).  Same candidates/INSERTC/count-stop/merge -> exact.
// QCHUNK hoist reverted (R6: dead weight).
#define INSERTC(Af, OI)                                                      \
  {                                                                          \
    float dot = q.x * (Af).x;                                                \
    dot = fmaf(q.y, (Af).y, dot);                                            \
    dot = fmaf(q.z, (Af).z, dot);                                            \
    float d2 = (qsq + (Af).w) - 2.0f * dot;                                  \
    unsigned u = __float_as_uint(d2);                                        \
    u ^= (0x80000000u | (unsigned)((int)u >> 31));                           \
    u64 key = ((u64)u << 32) | (OI);                                         \
    if (key < lst[15]) {                                                     \
      u64 x = key;                                                           \
      _Pragma("unroll") for (int p = 0; p < 16; ++p) {                       \
        bool sw = x < lst[p];                                                \
        u64 a = lst[p];                                                      \
        lst[p] = sw ? x : a;                                                 \
        x = sw ? a : x;                                                      \
      }                                                                      \
    }                                                                        \
  }

#define CSWAP(ia, ib)                                                        \
  {                                                                          \
    u64 ta = c[ia], tb2 = c[ib];                                             \
    bool sw = ta > tb2;                                                      \
    c[ia] = sw ? tb2 : ta;                                                   \
    c[ib] = sw ? ta : tb2;                                                   \
  }

__global__ __launch_bounds__(256) void k_query(const float4* __restrict__ spts,
                                               const u16* __restrict__ sidx,
                                               const int* __restrict__ offs,
                                               const float* __restrict__ gp,
                                               u16* __restrict__ oidx) {
  __shared__ int2 sgd[16 * 16];  // per-team segment table {incl_prefix, base}
  const int tid = threadIdx.x;
  const int l = tid & 15;       // team lane
  const int team = tid >> 4;    // 0..15 (query within block)
  const int lane = tid & 63;    // wave lane
  const int qid = blockIdx.x * 16 + team;
  const int b = qid >> 13, i = qid & 8191;
  const float4* __restrict__ sp = spts + (b << 13);
  const u16* __restrict__ sx = sidx + (b << 13);
  const int* __restrict__ ob = offs + b * NCELLP;
  const float* g = gp + b * 8;
  float4 q = sp[i];
  const float qsq = q.w;  // sq precomputed
  const unsigned orig = sx[i];
  const int cx = cellof(q.x, g[0], g[4]);
  const int cy = cellof(q.y, g[1], g[4]);
  const int cz = cellof(q.z, g[2], g[4]);
  const float s = g[3];

  u64 lst[16];
#pragma unroll
  for (int p = 0; p < 16; ++p) lst[p] = ~0ULL;

  const int tb = lane & 48;  // team base within wave
  const int tslot = team << 4;

  for (int r = 0; r <= GRID; ++r) {
    const int W = 2 * r + 1;
    const int nent = 2 * W * W;
    for (int cb = 0; cb < nent; cb += 16) {
      // phase A: each lane loads bounds of its own entry (parallel chains)
      int ms0 = 0, ms1 = 0;
      const int eid = cb + l;
      if (eid < nent) {
        const int rid = eid >> 1, side = eid & 1;
        const int dz = rid / W - r;
        const int dy = rid % W - r;
        const int z2 = cz + dz, y2 = cy + dy;
        if ((unsigned)z2 < GRID && (unsigned)y2 < GRID) {
          const int rowb = (z2 * GRID + y2) * GRID;
          const bool bdry = (dz == -r) || (dz == r) || (dy == -r) || (dy == r);
          if (bdry) {
            if (side == 0) {
              const int xl = cx - r < 0 ? 0 : cx - r;
              const int xh = cx + r > GRID - 1 ? GRID - 1 : cx + r;
              ms0 = ob[rowb + xl];
              ms1 = ob[rowb + xh + 1];
            }
          } else {
            const int x2 = side ? cx + r : cx - r;
            if ((unsigned)x2 < GRID) {
              ms0 = ob[rowb + x2];
              ms1 = ob[rowb + x2 + 1];
            }
          }
        }
      }
      // phase B: concatenate the 16 segments, deal flattened range.
      const int len = ms1 - ms0;  // >= 0
      int pre = len;
#pragma unroll
      for (int d = 1; d < 16; d <<= 1) {
        int u2 = __shfl_up(pre, d);
        if (l >= d) pre += u2;
      }
      const int total = __shfl(pre, tb + 15);
      if (total == 0) continue;
      sgd[tslot + l] = make_int2(pre, ms0 - (pre - len));
      int e = tslot;
      int2 sb = sgd[e];  // current segment {incl_prefix, base}
      for (int vidx = l; vidx < total; vidx += 16) {
        while (vidx >= sb.x) sb = sgd[++e];  // lane-local LDS advance
        const int j = sb.y + vidx;
        float4 A = sp[j];
        unsigned oi = sx[j];
        INSERTC(A, oi)
      }
    }
    // team stop check (R10): count team candidates with d2 <= (r*s)^2 - eps.
    const float rs = (float)r * s;
    const float T = fmaf(rs, rs, -1e-4f);
    unsigned tu = __float_as_uint(T);
    tu ^= (0x80000000u | (unsigned)((int)tu >> 31));
    int c = 0;
#pragma unroll
    for (int p = 0; p < 16; ++p) c += ((unsigned)(lst[p] >> 32) <= tu) ? 1 : 0;
    c += __shfl_xor(c, 1);
    c += __shfl_xor(c, 2);
    c += __shfl_xor(c, 4);
    c += __shfl_xor(c, 8);
    if (c >= 16) break;
  }

  // ---- in-register cross-lane merge (4 bitonic levels within team) ----
#pragma unroll
  for (int mm = 1; mm <= 8; mm <<= 1) {
    u64 c[16];
    const bool keepmin = (l & mm) == 0;
#pragma unroll
    for (int p = 0; p < 16; ++p) {
      u64 o = __shfl_xor(lst[15 - p], mm);
      u64 a = lst[p];
      u64 lo = a < o ? a : o;
      u64 hi = a < o ? o : a;
      c[p] = keepmin ? lo : hi;
    }
    CSWAP(0, 8) CSWAP(1, 9) CSWAP(2, 10) CSWAP(3, 11)
    CSWAP(4, 12) CSWAP(5, 13) CSWAP(6, 14) CSWAP(7, 15)
    CSWAP(0, 4) CSWAP(1, 5) CSWAP(2, 6) CSWAP(3, 7)
    CSWAP(8, 12) CSWAP(9, 13) CSWAP(10, 14) CSWAP(11, 15)
    CSWAP(0, 2) CSWAP(1, 3) CSWAP(4, 6) CSWAP(5, 7)
    CSWAP(8, 10) CSWAP(9, 11) CSWAP(12, 14) CSWAP(13, 15)
    CSWAP(0, 1) CSWAP(2, 3) CSWAP(4, 5) CSWAP(6, 7)
    CSWAP(8, 9) CSWAP(10, 11) CSWAP(12, 13) CSWAP(14, 15)
#pragma unroll
    for (int p = 0; p < 16; ++p) lst[p] = c[p];
  }

  if (l == 0) {  // lane 0 of each team holds the sorted team top-16
    unsigned pk[8];
#pragma unroll
    for (int k = 0; k < 16; k += 2)
      pk[k >> 1] = (unsigned)(lst[k] & 0xFFFFull) |
                   ((unsigned)(lst[k + 1] & 0xFFFFull) << 16);
    unsigned* od = (unsigned*)(oidx + (((size_t)(b << 13) + orig) << 4));
#pragma unroll
    for (int k = 0; k < 8; ++k) od[k] = pk[k];
  }
}

// ---------------------------------------------------------------- K6: lt = feat @ lt_w + lt_b
__global__ __launch_bounds__(256) void k_lt(const float* __restrict__ feat,
                                            const float* __restrict__ ltw,
                                            const float* __restrict__ ltb,
                                            float* __restrict__ lt) {
  __shared__ float sw[64][196];
  __shared__ float sf[32][68];
  const int tid = threadIdx.x;
  const int r0 = blockIdx.x * 32;
#pragma unroll
  for (int i = 0; i < 12; ++i) {
    int v = tid + i * 256;
    float4 w4 = ((const float4*)ltw)[v];
    int row = (v * 4) / 192, col = (v * 4) % 192;
    *(float4*)&sw[row][col] = w4;
  }
#pragma unroll
  for (int i = 0; i < 2; ++i) {
    int v = tid + i * 256;
    int row = v >> 4, c4 = v & 15;
    float4 f4 = ((const float4*)(feat + (size_t)(r0 + row) * 64))[c4];
    *(float4*)&sf[row][c4 * 4] = f4;
  }
  __syncthreads();
  const int r = tid >> 3;
  const int c0 = (tid & 7) * 24;
  float acc[24];
#pragma unroll
  for (int ll = 0; ll < 24; ++ll) acc[ll] = ltb[c0 + ll];
#pragma unroll 4
  for (int j = 0; j < 64; ++j) {
    float f = sf[r][j];
#pragma unroll
    for (int l4 = 0; l4 < 6; ++l4) {
      float4 w4 = *(const float4*)&sw[j][c0 + l4 * 4];
      acc[l4 * 4 + 0] = fmaf(f, w4.x, acc[l4 * 4 + 0]);
      acc[l4 * 4 + 1] = fmaf(f, w4.y, acc[l4 * 4 + 1]);
      acc[l4 * 4 + 2] = fmaf(f, w4.z, acc[l4 * 4 + 2]);
      acc[l4 * 4 + 3] = fmaf(f, w4.w, acc[l4 * 4 + 3]);
    }
  }
  float* orow = lt + (size_t)(r0 + r) * 192 + c0;
#pragma unroll
  for (int l4 = 0; l4 < 6; ++l4)
    *(float4*)&orow[l4 * 4] = make_float4(acc[l4 * 4], acc[l4 * 4 + 1],
                                          acc[l4 * 4 + 2], acc[l4 * 4 + 3]);
}

// ---------------------------------------------------------------- K7: main
// R12: online softmax (no pre/apd/xk arrays), prefetch-1 psi/alp gathers,
// DPP+readlane LN reductions (VALU pipe) instead of __shfl_xor (DS pipe).
// DPP ctrl must be a compile-time constant -> template parameter.
template <int CTRL>
__device__ __forceinline__ float dpp_add_f(float x) {
  int y = __builtin_amdgcn_update_dpp(0, __float_as_int(x), CTRL, 0xf, 0xf,
                                      true);
  return x + __int_as_float(y);
}
// full-wave (64-lane) sum -> wave-uniform via readlane 63.
// row_shr 1/2/4/8: lane15 of each row16 = row sum; row_bcast:15 add:
// lane31 = rows0+1, lane63 = rows2+3; row_bcast:31 add: lane63 = total.
__device__ __forceinline__ float wave_sum64(float x) {
  x = dpp_add_f<0x111>(x);  // row_shr:1
  x = dpp_add_f<0x112>(x);  // row_shr:2
  x = dpp_add_f<0x114>(x);  // row_shr:4
  x = dpp_add_f<0x118>(x);  // row_shr:8
  x = dpp_add_f<0x142>(x);  // row_bcast:15
  x = dpp_add_f<0x143>(x);  // row_bcast:31
  return __int_as_float(__builtin_amdgcn_readlane(__float_as_int(x), 63));
}

__global__ __launch_bounds__(256) void k_main(
    const float4* __restrict__ xytp, const float* __restrict__ lt,
    const u16* __restrict__ knn, const float* __restrict__ pe_w1,
    const float* __restrict__ pe_b1, const float* __restrict__ pe_w2,
    const float* __restrict__ pe_b2, const float* __restrict__ ln_g,
    const float* __restrict__ ln_b, float* __restrict__ out) {
  __shared__ float s_h[4][16][64];
  const int lane = threadIdx.x & 63;
  const int wave = threadIdx.x >> 6;
  const int pid = __builtin_amdgcn_readfirstlane(blockIdx.x * 4 + wave);
  const int b = pid >> 13;
  const int n = pid & 8191;

  float w1c[4];
#pragma unroll
  for (int d = 0; d < 4; ++d) w1c[d] = pe_w1[d * 64 + lane];
  const float b1c = pe_b1[lane];
  float w2c[64];
#pragma unroll
  for (int j = 0; j < 64; ++j) w2c[j] = pe_w2[j * 64 + lane];
  const float b2c = pe_b2[lane];
  const float gc = ln_g[lane], bc = ln_b[lane];

  int nb[16];
#pragma unroll
  for (int k = 0; k < 16; ++k) nb[k] = knn[pid * 16 + k];

  const float* __restrict__ ltb = lt + (size_t)(b << 13) * 192;
  const float vc = ltb[(size_t)n * 192 + lane];

  const float4 qv = xytp[(b << 13) + n];
#pragma unroll
  for (int k = 0; k < 16; ++k) {
    float4 g = xytp[(b << 13) + nb[k]];
    float r0 = qv.x - g.x, r1 = qv.y - g.y, r2 = qv.z - g.z, r3 = qv.w - g.w;
    float h = fmaf(r3, w1c[3],
                   fmaf(r2, w1c[2], fmaf(r1, w1c[1], fmaf(r0, w1c[0], b1c))));
    s_h[wave][k][lane] = fmaxf(h, 0.0f);
  }
  __syncthreads();

  float psi_c = ltb[(size_t)nb[0] * 192 + 64 + lane];
  float alp_c = ltb[(size_t)nb[0] * 192 + 128 + lane];
  float m = -INFINITY, se = 0.f, oacc = 0.f;
#pragma unroll
  for (int k = 0; k < 16; ++k) {
    float psi_n = 0.f, alp_n = 0.f;
    if (k < 15) {  // prefetch next neighbor's psi/alp (distance-1)
      const float* row = ltb + (size_t)nb[k + 1] * 192;
      psi_n = row[64 + lane];
      alp_n = row[128 + lane];
    }
    float acc = b2c;
#pragma unroll
    for (int j4 = 0; j4 < 16; ++j4) {
      float4 h4 = *(const float4*)&s_h[wave][k][j4 * 4];
      acc = fmaf(h4.x, w2c[j4 * 4 + 0], acc);
      acc = fmaf(h4.y, w2c[j4 * 4 + 1], acc);
      acc = fmaf(h4.z, w2c[j4 * 4 + 2], acc);
      acc = fmaf(h4.w, w2c[j4 * 4 + 3], acc);
    }
    const float pre = (vc - psi_c) + acc;
    const float apd = alp_c + acc;
    const float sm = wave_sum64(pre);
    const float ssm = wave_sum64(pre * pre);
    const float mu = sm * 0.015625f;
    const float var = fmaf(ssm, 0.015625f, -mu * mu);
    const float inv = rsqrtf(var + 1e-5f);
    const float x = fmaf((pre - mu) * inv, gc, bc) * 0.125f;
    // online softmax update (first iter: m=-inf -> corr = exp(-inf) = 0)
    const float mn = fmaxf(m, x);
    const float corr = __expf(m - mn);
    const float e = __expf(x - mn);
    se = fmaf(se, corr, e);
    oacc = fmaf(oacc, corr, e * apd);
    m = mn;
    psi_c = psi_n;
    alp_c = alp_n;
  }
  out[(size_t)pid * 64 + lane] = oacc / se;
}

// ---------------------------------------------------------------- launch
extern "C" void kernel_launch(void* const* d_in, const int* in_sizes, int n_in,
                              void* d_out, int out_size, void* d_ws,
                              size_t ws_size, hipStream_t stream) {
  const float4* xytp = (const float4*)d_in[0];
  const float* features = (const float*)d_in[1];
  const float* pe_w1 = (const float*)d_in[2];
  const float* pe_b1 = (const float*)d_in[3];
  const float* pe_w2 = (const float*)d_in[4];
  const float* pe_b2 = (const float*)d_in[5];
  const float* lt_w = (const float*)d_in[6];
  const float* lt_b = (const float*)d_in[7];
  const float* ln_g = (const float*)d_in[8];
  const float* ln_b = (const float*)d_in[9];
  float* out = (float*)d_out;

  char* ws = (char*)d_ws;
  u16* idxbuf = (u16*)(ws + WS_IDX);
  float* lt = (float*)(ws + WS_LT);
  int* cnt = (int*)(ws + WS_CNT);
  int* offs = (int*)(ws + WS_OFF);
  int* curs = (int*)(ws + WS_CUR);
  float4* spts = (float4*)(ws + WS_SP);
  float* gp = (float*)(ws + WS_GP);
  u16* sidx = (u16*)(ws + WS_SIDX);

  k_minmax<<<BATCH, 256, 0, stream>>>(xytp, gp, cnt);
  k_count<<<(BATCH * NPTS) / 256, 256, 0, stream>>>(xytp, gp, cnt);
  k_scan<<<BATCH, 1024, 0, stream>>>(cnt, offs, curs);
  k_scatter<<<(BATCH * NPTS) / 256, 256, 0, stream>>>(xytp, gp, curs, spts,
                                                      sidx);
  k_query<<<(BATCH * NPTS) / 16, 256, 0, stream>>>(spts, sidx, offs, gp,
                                                   idxbuf);
  k_lt<<<(BATCH * NPTS) / 32, 256, 0, stream>>>(features, lt_w, lt_b, lt);
  k_main<<<(BATCH * NPTS) / 4, 256, 0, stream>>>(xytp, lt, idxbuf, pe_w1,
                                                 pe_b1, pe_w2, pe_b2, ln_g,
                                                 ln_b, out);
}